// Round 8
// baseline (474.817 us; speedup 1.0000x reference)
//
#include <hip/hip_runtime.h>

#define NN 20000
#define NE 640000
#define NR 8
#define NB 8
#define HID 256
#define KPOI 12
#define KTIME 2880
#define KROAD 128
#define NK (NN * NR)   // 160000 (dst,rel) keys
#define SPLITK 5
#define KCH (KTIME / SPLITK)   // 576 = 9 x 64

typedef __attribute__((ext_vector_type(8))) short bf8_t;   // 8 bf16 = 4 VGPR
typedef __attribute__((ext_vector_type(4))) float f4_t;

__device__ inline unsigned short f2bf(float f) {  // RNE f32->bf16
  unsigned int u = __float_as_uint(f);
  u += 0x7FFF + ((u >> 16) & 1);
  return (unsigned short)(u >> 16);
}
__device__ inline float bf2f(unsigned short h) {
  return __uint_as_float((unsigned int)h << 16);
}

// -------- WT12[lr][o][i] = sum_b coef[lr][r,b]*basis[lr][b][i][o] (bf16) ----
// LDS-tiled: basis reads coalesced along o (256 B/wave); WT writes coalesced
// along i (128 B/wave). grid = 2*NR*16 blocks (16 = 4 i-tiles x 4 o-tiles).
__global__ __launch_bounds__(256) void make_WT_t(
    const float* __restrict__ coef1, const float* __restrict__ basis1,
    const float* __restrict__ coef2, const float* __restrict__ basis2,
    unsigned short* __restrict__ WT) {   // [2*NR][256][256]
  __shared__ unsigned short T[64][66];   // [i_loc][o_loc], +2 pad
  const int bid = blockIdx.x;
  const int lr = bid >> 4;              // 0..15
  const int it = (bid >> 2) & 3, ot = bid & 3;
  const int i0 = it * 64, o0 = ot * 64;
  const float* coef  = (lr < NR) ? coef1 : coef2;
  const float* basis = (lr < NR) ? basis1 : basis2;
  const int r = lr & 7;
  float cf[NB];
#pragma unroll
  for (int b = 0; b < NB; ++b) cf[b] = coef[r * NB + b];
  const int to = threadIdx.x & 63;
  const int tq = threadIdx.x >> 6;      // 0..3
#pragma unroll
  for (int k = 0; k < 16; ++k) {
    int i_loc = tq * 16 + k;
    int i = i0 + i_loc;
    float acc = 0.f;
#pragma unroll
    for (int b = 0; b < NB; ++b)
      acc += cf[b] * basis[((size_t)(b * HID + i)) * HID + o0 + to];
    T[i_loc][to] = f2bf(acc);
  }
  __syncthreads();
#pragma unroll
  for (int k = 0; k < 16; ++k) {
    int o_loc = tq * 16 + k;
    WT[(size_t)lr * HID * HID + (size_t)(o0 + o_loc) * HID + i0 + to] =
        T[to][o_loc];
  }
}

// -------- transpose both loop weights: L[l][c][r] = w_l[r][c] (bf16) --------
__global__ __launch_bounds__(256) void transp_LW(
    const float* __restrict__ w1, const float* __restrict__ w2,
    unsigned short* __restrict__ L1, unsigned short* __restrict__ L2) {
  int idx = blockIdx.x * 256 + threadIdx.x;   // < 2*65536
  int sel = idx >> 16;
  int j = idx & 65535;
  int r = j >> 8, c = j & 255;
  const float* in = sel ? w2 : w1;
  unsigned short* out = sel ? L2 : L1;
  out[c * HID + r] = f2bf(in[j]);
}

// ---------------- transpose + convert: out[c][r] = in[r][c] (bf16) ---------
__global__ __launch_bounds__(256) void transp_bf16(const float* __restrict__ in,
                                                   unsigned short* __restrict__ out,
                                                   int R, int Cc) {
  int idx = blockIdx.x * 256 + threadIdx.x;
  if (idx >= R * Cc) return;
  int r = idx / Cc, c = idx - r * Cc;
  out[(size_t)c * R + r] = f2bf(in[idx]);
}

// ---------------- small f32 GEMM -> bf16 out (poi / road projections) ------
#define BK 16
template<int BM, int BN, int TM, int TN>
__global__ __launch_bounds__(256) void sgemm_bf(
    int M, int Nn, int K,
    const float* __restrict__ A, int lda,
    const float* __restrict__ B, int ldb,
    const float* __restrict__ bias,
    unsigned short* __restrict__ C, int ldc)
{
  constexpr int SA = BM + 4;
  constexpr int SB = BN + 4;
  __shared__ float As[BK * SA];
  __shared__ float Bs[BK * SB];
  const int tid = threadIdx.x;
  const int brow = blockIdx.x * BM;
  const int bcol = blockIdx.y * BN;
  constexpr int TCOLS = BN / TN;
  const int row0 = (tid / TCOLS) * TM;
  const int col0 = (tid % TCOLS) * TN;

  float acc[TM][TN] = {};

  for (int kb = 0; kb < K; kb += BK) {
    constexpr int AIT = (BM * 4) / 256;
#pragma unroll
    for (int it = 0; it < AIT; ++it) {
      int i = tid + it * 256;
      int r = i >> 2, q = (i & 3) * 4;
      int grow = brow + r, gk = kb + q;
      if (grow < M && gk + 3 < K) {
        float4 v = *(const float4*)(A + (size_t)grow * lda + gk);
        As[(q + 0) * SA + r] = v.x;
        As[(q + 1) * SA + r] = v.y;
        As[(q + 2) * SA + r] = v.z;
        As[(q + 3) * SA + r] = v.w;
      } else {
#pragma unroll
        for (int j = 0; j < 4; ++j)
          As[(q + j) * SA + r] =
              (grow < M && gk + j < K) ? A[(size_t)grow * lda + gk + j] : 0.f;
      }
    }
    constexpr int BIT = (BN * 4) / 256;
#pragma unroll
    for (int it = 0; it < BIT; ++it) {
      int i = tid + it * 256;
      int k = i / (BN / 4), cq = (i % (BN / 4)) * 4;
      int gk = kb + k, gc = bcol + cq;
      float4 v = {0.f, 0.f, 0.f, 0.f};
      if (gk < K) {
        if (gc + 3 < Nn) {
          v = *(const float4*)(B + (size_t)gk * ldb + gc);
        } else {
#pragma unroll
          for (int j = 0; j < 4; ++j)
            if (gc + j < Nn) (&v.x)[j] = B[(size_t)gk * ldb + gc + j];
        }
      }
      *(float4*)(&Bs[k * SB + cq]) = v;
    }
    __syncthreads();
#pragma unroll
    for (int kk = 0; kk < BK; ++kk) {
      float a[TM], b[TN];
#pragma unroll
      for (int i = 0; i < TM; i += 4)
        *(float4*)(&a[i]) = *(const float4*)(&As[kk * SA + row0 + i]);
#pragma unroll
      for (int j = 0; j < TN; j += 4)
        *(float4*)(&b[j]) = *(const float4*)(&Bs[kk * SB + col0 + j]);
#pragma unroll
      for (int i = 0; i < TM; ++i)
#pragma unroll
        for (int j = 0; j < TN; ++j)
          acc[i][j] += a[i] * b[j];
    }
    __syncthreads();
  }

  float bcache[TN];
#pragma unroll
  for (int j = 0; j < TN; ++j)
    bcache[j] = bias ? bias[bcol + col0 + j] : 0.f;
#pragma unroll
  for (int i = 0; i < TM; ++i) {
    int row = brow + row0 + i;
    if (row >= M) continue;
#pragma unroll
    for (int j = 0; j < TN; ++j) {
      int col = bcol + col0 + j;
      if (col < Nn)
        C[(size_t)row * ldc + col] = f2bf(acc[i][j] + bcache[j]);
    }
  }
}

// ---------------- split-K time GEMM: TP[kc] = time_dist[:, kc-chunk] @ TWT^T
__global__ __launch_bounds__(256) void mfma_time_sk(
    const float* __restrict__ A,            // [NN][2880] f32
    const unsigned short* __restrict__ BT,  // [128][2880] bf16
    float* __restrict__ TP)                 // [SPLITK][NN][128]
{
  __shared__ __align__(16) char ldsA[32 * 128];
  __shared__ __align__(16) char ldsB[128 * 128];
  const int tid = threadIdx.x;
  const int lane = tid & 63;
  const int w = tid >> 6;            // 0..3 -> col block w*32
  const int brow = blockIdx.x * 32;
  const int kb0 = blockIdx.y * KCH;

  f4_t acc[2][2];
#pragma unroll
  for (int i = 0; i < 2; ++i)
#pragma unroll
    for (int j = 0; j < 2; ++j) acc[i][j] = (f4_t){0.f, 0.f, 0.f, 0.f};

  for (int kb = kb0; kb < kb0 + KCH; kb += 64) {
    {  // A: 32 rows x 64 k, f32 -> bf16
      int r = tid >> 3, c8 = tid & 7;
      const float* ap = A + (size_t)(brow + r) * KTIME + kb + c8 * 8;
      f4_t v0 = *(const f4_t*)ap;
      f4_t v1 = *(const f4_t*)(ap + 4);
      unsigned short hh[8];
#pragma unroll
      for (int j = 0; j < 4; ++j) { hh[j] = f2bf(v0[j]); hh[4 + j] = f2bf(v1[j]); }
      *(bf8_t*)(ldsA + r * 128 + ((c8 * 16) ^ ((r & 7) << 4))) = *(bf8_t*)hh;
    }
#pragma unroll
    for (int it = 0; it < 4; ++it) {  // B: 128 rows x 64 k
      int slot = tid + it * 256;
      int r = slot >> 3, c8 = slot & 7;
      bf8_t v = *(const bf8_t*)(BT + (size_t)r * KTIME + kb + c8 * 8);
      *(bf8_t*)(ldsB + r * 128 + ((c8 * 16) ^ ((r & 7) << 4))) = v;
    }
    __syncthreads();
#pragma unroll
    for (int ks = 0; ks < 2; ++ks) {
      const int kbyte = ks * 64 + (lane >> 4) * 16;
      bf8_t af[2], bfr[2];
#pragma unroll
      for (int mi = 0; mi < 2; ++mi) {
        int m = mi * 16 + (lane & 15);
        af[mi] = *(const bf8_t*)(ldsA + m * 128 + (kbyte ^ ((m & 7) << 4)));
      }
#pragma unroll
      for (int ni = 0; ni < 2; ++ni) {
        int n = w * 32 + ni * 16 + (lane & 15);
        bfr[ni] = *(const bf8_t*)(ldsB + n * 128 + (kbyte ^ ((n & 7) << 4)));
      }
#pragma unroll
      for (int mi = 0; mi < 2; ++mi)
#pragma unroll
        for (int ni = 0; ni < 2; ++ni)
          acc[mi][ni] = __builtin_amdgcn_mfma_f32_16x16x32_bf16(
              af[mi], bfr[ni], acc[mi][ni], 0, 0, 0);
    }
    __syncthreads();
  }

  float* tp = TP + (size_t)blockIdx.y * NN * 128;
  const int rq = (lane >> 4) * 4;
  const int cl = lane & 15;
#pragma unroll
  for (int ni = 0; ni < 2; ++ni) {
    int c = w * 32 + ni * 16 + cl;
#pragma unroll
    for (int mi = 0; mi < 2; ++mi) {
#pragma unroll
      for (int j = 0; j < 4; ++j) {
        int row = brow + mi * 16 + rq + j;
        tp[(size_t)row * 128 + c] = acc[mi][ni][j];
      }
    }
  }
}

// ---------------- time finish: featb[:,64:192] = bf16(sum_k TP + bias) -----
__global__ __launch_bounds__(256) void time_finish(
    const float* __restrict__ TP, const float* __restrict__ bias,
    unsigned short* __restrict__ featb) {
  int i = blockIdx.x * 256 + threadIdx.x;   // over NN*32 float4 groups
  if (i >= NN * 32) return;
  int row = i >> 5, c4 = (i & 31) * 4;
  f4_t s = *(const f4_t*)(TP + (size_t)row * 128 + c4);
#pragma unroll
  for (int k = 1; k < SPLITK; ++k) {
    f4_t v = *(const f4_t*)(TP + (size_t)k * NN * 128 + (size_t)row * 128 + c4);
    s.x += v.x; s.y += v.y; s.z += v.z; s.w += v.w;
  }
  f4_t b = *(const f4_t*)(bias + c4);
  unsigned short h[4] = {f2bf(s.x + b.x), f2bf(s.y + b.y),
                         f2bf(s.z + b.z), f2bf(s.w + b.w)};
  *(ushort4*)(featb + (size_t)row * 256 + 64 + c4) = *(ushort4*)h;
}

// ---------------- transform GEMM: Y[s] = hin @ W_s^T for s=0..7, Y[8]=hin@LWT
// block = 64 rows x 256 cols, 8 waves; grid 313. A staged ONCE per block.
__global__ __launch_bounds__(512) void gemm_y(
    const unsigned short* __restrict__ hin,  // [NN][256] bf16
    const unsigned short* __restrict__ WT,   // [NR][256][256] bf16 (o-major)
    const unsigned short* __restrict__ LWT,  // [256][256] bf16 loop_w^T
    unsigned short* __restrict__ Y)          // [NR+1][NN][256] bf16
{
  __shared__ __align__(16) char At[64 * 512];    // 32 KB, swizzled
  __shared__ __align__(16) char Bt[256 * 128];   // 32 KB, swizzled
  const int tid = threadIdx.x;
  const int lane = tid & 63;
  const int w = tid >> 6;        // 0..7
  const int wr = w >> 1;         // 0..3: rows wr*16..+15
  const int wc = w & 1;          // 0..1: cols wc*128..+127
  const int brow = blockIdx.x * 64;

  // ---- stage A tile once: 64 rows x 256 bf16 (2048 x 16B slots) ----
#pragma unroll
  for (int it = 0; it < 4; ++it) {
    int slot = tid + it * 512;
    int r = slot >> 5, c16 = slot & 31;
    bf8_t v = {0, 0, 0, 0, 0, 0, 0, 0};
    int grow = brow + r;
    if (grow < NN) v = *(const bf8_t*)(hin + (size_t)grow * HID + c16 * 8);
    *(bf8_t*)(At + r * 512 + ((c16 * 16) ^ ((r & 7) << 4))) = v;
  }
  __syncthreads();

  const int rq = (lane >> 4) * 4;
  const int cl = lane & 15;

#pragma unroll 1
  for (int s = 0; s < NR + 1; ++s) {
    const unsigned short* Wsrc = (s < NR) ? (WT + (size_t)s * HID * HID) : LWT;
    f4_t acc[8];
#pragma unroll
    for (int i = 0; i < 8; ++i) acc[i] = (f4_t){0.f, 0.f, 0.f, 0.f};
#pragma unroll 1
    for (int kc = 0; kc < 4; ++kc) {
#pragma unroll
      for (int it = 0; it < 4; ++it) {  // stage W chunk: 256 n-rows x 64 k
        int slot = tid + it * 512;
        int n = slot >> 3, c8 = slot & 7;
        bf8_t v = *(const bf8_t*)(Wsrc + (size_t)n * HID + kc * 64 + c8 * 8);
        *(bf8_t*)(Bt + n * 128 + ((c8 * 16) ^ ((n & 7) << 4))) = v;
      }
      __syncthreads();
#pragma unroll
      for (int ks = 0; ks < 2; ++ks) {
        const int kbyte = ks * 64 + (lane >> 4) * 16;
        int m = wr * 16 + (lane & 15);
        bf8_t af = *(const bf8_t*)(
            At + m * 512 + ((kc * 128 + kbyte) ^ ((m & 7) << 4)));
#pragma unroll
        for (int ni = 0; ni < 8; ++ni) {
          int n = wc * 128 + ni * 16 + (lane & 15);
          bf8_t bfr = *(const bf8_t*)(Bt + n * 128 + (kbyte ^ ((n & 7) << 4)));
          acc[ni] = __builtin_amdgcn_mfma_f32_16x16x32_bf16(af, bfr, acc[ni], 0, 0, 0);
        }
      }
      __syncthreads();
    }
    // ---- slice epilogue: write Y[s] bf16 ----
    unsigned short* Ys = Y + (size_t)s * NN * HID;
#pragma unroll
    for (int ni = 0; ni < 8; ++ni) {
      int c = wc * 128 + ni * 16 + cl;
#pragma unroll
      for (int j = 0; j < 4; ++j) {
        int row = brow + wr * 16 + rq + j;
        if (row < NN) Ys[(size_t)row * HID + c] = f2bf(acc[ni][j]);
      }
    }
  }
}

// ---------------- gather: out[d] = bias + Y[8][d] + sum_r sum_e Y[r][src_e] -
// one wave per dst node; EPI 1: hb = bf16(relu(.)), EPI 0: C = f32(.)
template<int EPI>
__global__ __launch_bounds__(256) void gather_k(
    const int* __restrict__ offs, const unsigned short* __restrict__ ssrc,
    const unsigned short* __restrict__ Y,    // [NR+1][NN][256]
    const float* __restrict__ bias,
    unsigned short* __restrict__ hb, float* __restrict__ C)
{
  int d = (blockIdx.x * 256 + threadIdx.x) >> 6;
  int lane = threadIdx.x & 63;
  if (d >= NN) return;
  const size_t SL = (size_t)NN * HID;

  f4_t acc = *(const f4_t*)(bias + lane * 4);
  {  // self-loop slice
    ushort4 u = *(const ushort4*)(Y + (size_t)NR * SL + (size_t)d * HID + lane * 4);
    acc.x += bf2f(u.x); acc.y += bf2f(u.y);
    acc.z += bf2f(u.z); acc.w += bf2f(u.w);
  }
  int o[NR + 1];
#pragma unroll
  for (int r = 0; r <= NR; ++r) o[r] = offs[d * NR + r];
#pragma unroll 1
  for (int r = 0; r < NR; ++r) {
    const unsigned short* Yr = Y + (size_t)r * SL;
    int e = o[r], hi = o[r + 1];
    for (; e + 2 <= hi; e += 2) {
      int s0 = ssrc[e], s1 = ssrc[e + 1];
      ushort4 u0 = *(const ushort4*)(Yr + (size_t)s0 * HID + lane * 4);
      ushort4 u1 = *(const ushort4*)(Yr + (size_t)s1 * HID + lane * 4);
      acc.x += bf2f(u0.x) + bf2f(u1.x);
      acc.y += bf2f(u0.y) + bf2f(u1.y);
      acc.z += bf2f(u0.z) + bf2f(u1.z);
      acc.w += bf2f(u0.w) + bf2f(u1.w);
    }
    if (e < hi) {
      int s = ssrc[e];
      ushort4 u = *(const ushort4*)(Yr + (size_t)s * HID + lane * 4);
      acc.x += bf2f(u.x); acc.y += bf2f(u.y);
      acc.z += bf2f(u.z); acc.w += bf2f(u.w);
    }
  }
  if (EPI == 1) {
    unsigned short h[4] = {f2bf(fmaxf(acc.x, 0.f)), f2bf(fmaxf(acc.y, 0.f)),
                           f2bf(fmaxf(acc.z, 0.f)), f2bf(fmaxf(acc.w, 0.f))};
    *(ushort4*)(hb + (size_t)d * HID + lane * 4) = *(ushort4*)h;
  } else {
    *(f4_t*)(C + (size_t)d * HID + lane * 4) = acc;
  }
}

// ---------------- CSR build: key = dst*NR + etype ----------------
__global__ __launch_bounds__(256) void hist_k(const int* __restrict__ dst,
                                              const int* __restrict__ et,
                                              int* __restrict__ counts) {
  int e = blockIdx.x * 256 + threadIdx.x;
  if (e < NE) atomicAdd(&counts[dst[e] * NR + et[e]], 1);
}

__global__ __launch_bounds__(256) void scan_block(const int* __restrict__ counts,
                                                  int* __restrict__ offs,
                                                  int* __restrict__ bsums) {
  __shared__ int sh[256];
  int base = blockIdx.x * 1024;
  int t = threadIdx.x;
  int v[4];
  int s = 0;
#pragma unroll
  for (int j = 0; j < 4; ++j) {
    int idx = base + t * 4 + j;
    v[j] = (idx < NK) ? counts[idx] : 0;
    s += v[j];
  }
  sh[t] = s;
  __syncthreads();
  for (int off = 1; off < 256; off <<= 1) {
    int x = (t >= off) ? sh[t - off] : 0;
    __syncthreads();
    sh[t] += x;
    __syncthreads();
  }
  int run = sh[t] - s;
#pragma unroll
  for (int j = 0; j < 4; ++j) {
    int idx = base + t * 4 + j;
    if (idx < NK) offs[idx] = run;
    run += v[j];
  }
  if (t == 255) bsums[blockIdx.x] = sh[255];
}

__global__ __launch_bounds__(256) void scan_bsums(int* __restrict__ bsums, int nblk) {
  __shared__ int sh[256];
  int t = threadIdx.x;
  int own = (t < nblk) ? bsums[t] : 0;
  sh[t] = own;
  __syncthreads();
  for (int off = 1; off < 256; off <<= 1) {
    int x = (t >= off) ? sh[t - off] : 0;
    __syncthreads();
    sh[t] += x;
    __syncthreads();
  }
  int ex = sh[t] - own;
  if (t < nblk) bsums[t] = ex;
}

// writes final offs AND cursor copy
__global__ __launch_bounds__(256) void add_base(int* __restrict__ offs,
                                                const int* __restrict__ bsums,
                                                int* __restrict__ cursor) {
  int idx = blockIdx.x * 256 + threadIdx.x;
  if (idx < NK) {
    int v = offs[idx] + bsums[idx >> 10];
    offs[idx] = v;
    cursor[idx] = v;
  }
  if (idx == NK) offs[NK] = NE;
}

__global__ __launch_bounds__(256) void fill_k(const int* __restrict__ src,
                                              const int* __restrict__ dst,
                                              const int* __restrict__ et,
                                              int* __restrict__ cursor,
                                              unsigned short* __restrict__ ssrc) {
  int e = blockIdx.x * 256 + threadIdx.x;
  if (e < NE) {
    int key = dst[e] * NR + et[e];
    int p = atomicAdd(&cursor[key], 1);
    ssrc[p] = (unsigned short)src[e];
  }
}

extern "C" void kernel_launch(void* const* d_in, const int* in_sizes, int n_in,
                              void* d_out, int out_size, void* d_ws, size_t ws_size,
                              hipStream_t stream) {
  const int*   srcp      = (const int*)d_in[0];
  const int*   dstp      = (const int*)d_in[1];
  const int*   etypep    = (const int*)d_in[2];
  const float* poi_dist  = (const float*)d_in[3];
  const float* time_dist = (const float*)d_in[4];
  const float* road_feat = (const float*)d_in[5];
  const float* poi_w     = (const float*)d_in[6];
  const float* poi_b     = (const float*)d_in[7];
  const float* time_w    = (const float*)d_in[8];
  const float* time_b    = (const float*)d_in[9];
  const float* road_w    = (const float*)d_in[10];
  const float* road_b    = (const float*)d_in[11];
  const float* basis1    = (const float*)d_in[12];
  const float* coef1     = (const float*)d_in[13];
  const float* loop_w1   = (const float*)d_in[14];
  const float* bias1     = (const float*)d_in[15];
  const float* basis2    = (const float*)d_in[16];
  const float* coef2     = (const float*)d_in[17];
  const float* loop_w2   = (const float*)d_in[18];
  const float* bias2     = (const float*)d_in[19];

  float* out = (float*)d_out;

  // ws layout (bytes), total ~158.6 MB (ws_size ~921 MB):
  //   WT12 bf16 @ 0           (2,097,152)   [2*NR][256][256] relation W^T
  //   LWT1 bf16 @ 2,097,152   (131,072)
  //   LWT2 bf16 @ 2,228,224   (131,072)
  //   TWT  bf16 @ 2,359,296   (737,280)     time_w^T
  //   hbuf bf16 @ 3,096,576   (10,240,000)  featb in L1; relu(h1) bf16 in L2
  //   Y    bf16 @ 13,336,576  (92,160,000)  9 transform slices (N x 256 each)
  //   TP   f32  @ 105,496,576 (51,200,000)  split-K time partials
  //   offs      @ 156,696,576 (640,016)
  //   bsums     @ 157,336,592 (1,024)
  //   ssrc u16  @ 157,337,616 (1,280,000)
  // aliases (dead before host region's first real write):
  //   counts -> Y region, cursor -> TP region
  char* ws = (char*)d_ws;
  unsigned short* WT12   = (unsigned short*)(ws);
  unsigned short* LWT1   = (unsigned short*)(ws + 2097152);
  unsigned short* LWT2   = (unsigned short*)(ws + 2228224);
  unsigned short* TWT    = (unsigned short*)(ws + 2359296);
  unsigned short* hbuf   = (unsigned short*)(ws + 3096576);
  unsigned short* Y      = (unsigned short*)(ws + 13336576);
  float*          TP     = (float*)(ws + 105496576);
  int*            offs   = (int*)  (ws + 156696576);
  int*            bsums  = (int*)  (ws + 157336592);
  unsigned short* ssrc   = (unsigned short*)(ws + 157337616);
  int*            counts = (int*)Y;
  int*            cursor = (int*)TP;

  unsigned short* WT1 = WT12;
  unsigned short* WT2 = WT12 + (size_t)NR * HID * HID;

  dim3 blk(256);
  const int MG64 = (NN + 63) / 64;  // 313

  // ---- CSR build (aliases dead before Y/TP first writes) ----
  hipMemsetAsync(counts, 0, NK * sizeof(int), stream);
  hist_k<<<NE / 256, blk, 0, stream>>>(dstp, etypep, counts);
  scan_block<<<(NK + 1023) / 1024, blk, 0, stream>>>(counts, offs, bsums);
  scan_bsums<<<1, blk, 0, stream>>>(bsums, (NK + 1023) / 1024);
  add_base<<<(NK + 1 + 255) / 256, blk, 0, stream>>>(offs, bsums, cursor);
  fill_k<<<NE / 256, blk, 0, stream>>>(srcp, dstp, etypep, cursor, ssrc);

  // ---- weight preprocessing ----
  transp_LW<<<2 * HID * HID / 256, blk, 0, stream>>>(loop_w1, loop_w2, LWT1, LWT2);
  transp_bf16<<<(KTIME * 128 + 255) / 256, blk, 0, stream>>>(time_w, TWT, KTIME, 128);
  make_WT_t<<<2 * NR * 16, blk, 0, stream>>>(coef1, basis1, coef2, basis2, WT12);

  // ---- input projections -> hbuf (N x 256 bf16) ----
  sgemm_bf<64, 64, 4, 4><<<dim3(MG64, 1), blk, 0, stream>>>(
      NN, 64, KPOI, poi_dist, KPOI, poi_w, 64, poi_b, hbuf + 0, HID);
  mfma_time_sk<<<dim3(NN / 32, SPLITK), blk, 0, stream>>>(time_dist, TWT, TP);
  time_finish<<<(NN * 32 + 255) / 256, blk, 0, stream>>>(TP, time_b, hbuf);
  sgemm_bf<64, 64, 4, 4><<<dim3(MG64, 1), blk, 0, stream>>>(
      NN, 64, KROAD, road_feat, KROAD, road_w, 64, road_b, hbuf + 192, HID);

  // ---- layer 1: Y = transforms(hbuf); hbuf = bf16(relu(gather(Y))) ----
  gemm_y<<<MG64, 512, 0, stream>>>(hbuf, WT1, LWT1, Y);
  gather_k<1><<<(NN + 3) / 4, blk, 0, stream>>>(offs, ssrc, Y, bias1, hbuf, nullptr);

  // ---- layer 2: Y = transforms(hbuf); out = gather(Y) (f32) ----
  gemm_y<<<MG64, 512, 0, stream>>>(hbuf, WT2, LWT2, Y);
  gather_k<0><<<(NN + 3) / 4, blk, 0, stream>>>(offs, ssrc, Y, bias2, nullptr, out);
}

// Round 9
// 462.077 us; speedup vs baseline: 1.0276x; 1.0276x over previous
//
#include <hip/hip_runtime.h>

#define NN 20000
#define NE 640000
#define NR 8
#define NB 8
#define HID 256
#define KPOI 12
#define KTIME 2880
#define KROAD 128
#define NK (NN * NR)   // 160000 (dst,rel) keys
#define SPLITK 5
#define KCH (KTIME / SPLITK)   // 576 = 9 x 64

typedef __attribute__((ext_vector_type(8))) short bf8_t;   // 8 bf16 = 4 VGPR
typedef __attribute__((ext_vector_type(4))) float f4_t;

__device__ inline unsigned short f2bf(float f) {  // RNE f32->bf16
  unsigned int u = __float_as_uint(f);
  u += 0x7FFF + ((u >> 16) & 1);
  return (unsigned short)(u >> 16);
}
__device__ inline float bf2f(unsigned short h) {
  return __uint_as_float((unsigned int)h << 16);
}

// ---------------- fused weight prep: one launch, 3 independent jobs --------
// blocks [0,512): loop_w1/2 transpose; [512,1952): time_w transpose;
// [1952,2208): basis-contraction W^T (LDS-tiled, coalesced both sides)
__global__ __launch_bounds__(256) void prep_k(
    const float* __restrict__ loop_w1, const float* __restrict__ loop_w2,
    const float* __restrict__ time_w,
    const float* __restrict__ coef1, const float* __restrict__ basis1,
    const float* __restrict__ coef2, const float* __restrict__ basis2,
    unsigned short* __restrict__ LWT1, unsigned short* __restrict__ LWT2,
    unsigned short* __restrict__ TWT, unsigned short* __restrict__ WT12)
{
  __shared__ unsigned short T[64][66];
  const int b = blockIdx.x;
  if (b < 512) {          // loop-weight transpose: L[c][r] = w[r][c]
    int idx = b * 256 + threadIdx.x;
    int sel = idx >> 16;
    int j = idx & 65535;
    int r = j >> 8, c = j & 255;
    const float* in = sel ? loop_w2 : loop_w1;
    unsigned short* o = sel ? LWT2 : LWT1;
    o[c * HID + r] = f2bf(in[j]);
  } else if (b < 1952) {  // time_w transpose: TWT[c][r] = time_w[r][c]
    int idx = (b - 512) * 256 + threadIdx.x;   // < 368640 exact
    int r = idx >> 7, c = idx & 127;
    TWT[(size_t)c * KTIME + r] = f2bf(time_w[idx]);
  } else {                // WT12[lr][o][i] = sum_b coef*basis[b][i][o]
    const int bid = b - 1952;
    const int lr = bid >> 4;
    const int it = (bid >> 2) & 3, ot = bid & 3;
    const int i0 = it * 64, o0 = ot * 64;
    const float* coef  = (lr < NR) ? coef1 : coef2;
    const float* basis = (lr < NR) ? basis1 : basis2;
    const int r = lr & 7;
    float cf[NB];
#pragma unroll
    for (int q = 0; q < NB; ++q) cf[q] = coef[r * NB + q];
    const int to = threadIdx.x & 63;
    const int tq = threadIdx.x >> 6;
#pragma unroll
    for (int k = 0; k < 16; ++k) {
      int i_loc = tq * 16 + k;
      int i = i0 + i_loc;
      float acc = 0.f;
#pragma unroll
      for (int q = 0; q < NB; ++q)
        acc += cf[q] * basis[((size_t)(q * HID + i)) * HID + o0 + to];
      T[i_loc][to] = f2bf(acc);
    }
    __syncthreads();
#pragma unroll
    for (int k = 0; k < 16; ++k) {
      int o_loc = tq * 16 + k;
      WT12[(size_t)lr * HID * HID + (size_t)(o0 + o_loc) * HID + i0 + to] =
          T[to][o_loc];
    }
  }
}

// ---------------- f32 GEMM tile body (device fn; poi/road projections) -----
#define BK 16
__device__ inline void sgemm_body(
    int M, int Nn, int K,
    const float* __restrict__ A, int lda,
    const float* __restrict__ B, int ldb,
    const float* __restrict__ bias,
    unsigned short* __restrict__ C, int ldc, int brow)
{
  constexpr int BM = 64, BN = 64, TM = 4, TN = 4;
  constexpr int SA = BM + 4;
  constexpr int SB = BN + 4;
  __shared__ float As[BK * SA];
  __shared__ float Bs[BK * SB];
  const int tid = threadIdx.x;
  constexpr int TCOLS = BN / TN;
  const int row0 = (tid / TCOLS) * TM;
  const int col0 = (tid % TCOLS) * TN;

  float acc[TM][TN] = {};

  for (int kb = 0; kb < K; kb += BK) {
    {
      int i = tid;
      int r = i >> 2, q = (i & 3) * 4;
      int grow = brow + r, gk = kb + q;
      if (grow < M && gk + 3 < K) {
        float4 v = *(const float4*)(A + (size_t)grow * lda + gk);
        As[(q + 0) * SA + r] = v.x;
        As[(q + 1) * SA + r] = v.y;
        As[(q + 2) * SA + r] = v.z;
        As[(q + 3) * SA + r] = v.w;
      } else {
#pragma unroll
        for (int j = 0; j < 4; ++j)
          As[(q + j) * SA + r] =
              (grow < M && gk + j < K) ? A[(size_t)grow * lda + gk + j] : 0.f;
      }
    }
    {
      int i = tid;
      int k = i / (BN / 4), cq = (i % (BN / 4)) * 4;
      int gk = kb + k;
      float4 v = {0.f, 0.f, 0.f, 0.f};
      if (gk < K) {
        if (cq + 3 < Nn) {
          v = *(const float4*)(B + (size_t)gk * ldb + cq);
        } else {
#pragma unroll
          for (int j = 0; j < 4; ++j)
            if (cq + j < Nn) (&v.x)[j] = B[(size_t)gk * ldb + cq + j];
        }
      }
      *(float4*)(&Bs[k * SB + cq]) = v;
    }
    __syncthreads();
#pragma unroll
    for (int kk = 0; kk < BK; ++kk) {
      float a[TM], bb[TN];
      *(float4*)(&a[0]) = *(const float4*)(&As[kk * SA + row0]);
      *(float4*)(&bb[0]) = *(const float4*)(&Bs[kk * SB + col0]);
#pragma unroll
      for (int i = 0; i < TM; ++i)
#pragma unroll
        for (int j = 0; j < TN; ++j)
          acc[i][j] += a[i] * bb[j];
    }
    __syncthreads();
  }

  float bcache[TN];
#pragma unroll
  for (int j = 0; j < TN; ++j) bcache[j] = bias[col0 + j];
#pragma unroll
  for (int i = 0; i < TM; ++i) {
    int row = brow + row0 + i;
    if (row >= M) continue;
#pragma unroll
    for (int j = 0; j < TN; ++j)
      C[(size_t)row * ldc + col0 + j] = f2bf(acc[i][j] + bcache[j]);
  }
}

// poi (y=0) and road (y=1) projections in ONE launch; grid (313, 2)
__global__ __launch_bounds__(256) void proj2_k(
    const float* __restrict__ poi_dist, const float* __restrict__ poi_w,
    const float* __restrict__ poi_b,
    const float* __restrict__ road_feat, const float* __restrict__ road_w,
    const float* __restrict__ road_b,
    unsigned short* __restrict__ hbuf)
{
  const int brow = blockIdx.x * 64;
  if (blockIdx.y == 0)
    sgemm_body(NN, 64, KPOI, poi_dist, KPOI, poi_w, 64, poi_b,
               hbuf + 0, HID, brow);
  else
    sgemm_body(NN, 64, KROAD, road_feat, KROAD, road_w, 64, road_b,
               hbuf + 192, HID, brow);
}

// ---------------- split-K time GEMM: TP[kc] = time_dist[:, kc-chunk] @ TWT^T
__global__ __launch_bounds__(256) void mfma_time_sk(
    const float* __restrict__ A,            // [NN][2880] f32
    const unsigned short* __restrict__ BT,  // [128][2880] bf16
    float* __restrict__ TP)                 // [SPLITK][NN][128]
{
  __shared__ __align__(16) char ldsA[32 * 128];
  __shared__ __align__(16) char ldsB[128 * 128];
  const int tid = threadIdx.x;
  const int lane = tid & 63;
  const int w = tid >> 6;            // 0..3 -> col block w*32
  const int brow = blockIdx.x * 32;
  const int kb0 = blockIdx.y * KCH;

  f4_t acc[2][2];
#pragma unroll
  for (int i = 0; i < 2; ++i)
#pragma unroll
    for (int j = 0; j < 2; ++j) acc[i][j] = (f4_t){0.f, 0.f, 0.f, 0.f};

  for (int kb = kb0; kb < kb0 + KCH; kb += 64) {
    {  // A: 32 rows x 64 k, f32 -> bf16
      int r = tid >> 3, c8 = tid & 7;
      const float* ap = A + (size_t)(brow + r) * KTIME + kb + c8 * 8;
      f4_t v0 = *(const f4_t*)ap;
      f4_t v1 = *(const f4_t*)(ap + 4);
      unsigned short hh[8];
#pragma unroll
      for (int j = 0; j < 4; ++j) { hh[j] = f2bf(v0[j]); hh[4 + j] = f2bf(v1[j]); }
      *(bf8_t*)(ldsA + r * 128 + ((c8 * 16) ^ ((r & 7) << 4))) = *(bf8_t*)hh;
    }
#pragma unroll
    for (int it = 0; it < 4; ++it) {  // B: 128 rows x 64 k
      int slot = tid + it * 256;
      int r = slot >> 3, c8 = slot & 7;
      bf8_t v = *(const bf8_t*)(BT + (size_t)r * KTIME + kb + c8 * 8);
      *(bf8_t*)(ldsB + r * 128 + ((c8 * 16) ^ ((r & 7) << 4))) = v;
    }
    __syncthreads();
#pragma unroll
    for (int ks = 0; ks < 2; ++ks) {
      const int kbyte = ks * 64 + (lane >> 4) * 16;
      bf8_t af[2], bfr[2];
#pragma unroll
      for (int mi = 0; mi < 2; ++mi) {
        int m = mi * 16 + (lane & 15);
        af[mi] = *(const bf8_t*)(ldsA + m * 128 + (kbyte ^ ((m & 7) << 4)));
      }
#pragma unroll
      for (int ni = 0; ni < 2; ++ni) {
        int n = w * 32 + ni * 16 + (lane & 15);
        bfr[ni] = *(const bf8_t*)(ldsB + n * 128 + (kbyte ^ ((n & 7) << 4)));
      }
#pragma unroll
      for (int mi = 0; mi < 2; ++mi)
#pragma unroll
        for (int ni = 0; ni < 2; ++ni)
          acc[mi][ni] = __builtin_amdgcn_mfma_f32_16x16x32_bf16(
              af[mi], bfr[ni], acc[mi][ni], 0, 0, 0);
    }
    __syncthreads();
  }

  float* tp = TP + (size_t)blockIdx.y * NN * 128;
  const int rq = (lane >> 4) * 4;
  const int cl = lane & 15;
#pragma unroll
  for (int ni = 0; ni < 2; ++ni) {
    int c = w * 32 + ni * 16 + cl;
#pragma unroll
    for (int mi = 0; mi < 2; ++mi) {
#pragma unroll
      for (int j = 0; j < 4; ++j) {
        int row = brow + mi * 16 + rq + j;
        tp[(size_t)row * 128 + c] = acc[mi][ni][j];
      }
    }
  }
}

// ---------------- time finish: hbuf[:,64:192] = bf16(sum_k TP + bias) ------
__global__ __launch_bounds__(256) void time_finish(
    const float* __restrict__ TP, const float* __restrict__ bias,
    unsigned short* __restrict__ featb) {
  int i = blockIdx.x * 256 + threadIdx.x;   // over NN*32 float4 groups
  if (i >= NN * 32) return;
  int row = i >> 5, c4 = (i & 31) * 4;
  f4_t s = *(const f4_t*)(TP + (size_t)row * 128 + c4);
#pragma unroll
  for (int k = 1; k < SPLITK; ++k) {
    f4_t v = *(const f4_t*)(TP + (size_t)k * NN * 128 + (size_t)row * 128 + c4);
    s.x += v.x; s.y += v.y; s.z += v.z; s.w += v.w;
  }
  f4_t b = *(const f4_t*)(bias + c4);
  unsigned short h[4] = {f2bf(s.x + b.x), f2bf(s.y + b.y),
                         f2bf(s.z + b.z), f2bf(s.w + b.w)};
  *(ushort4*)(featb + (size_t)row * 256 + 64 + c4) = *(ushort4*)h;
}

// ---------------- CSR segment aggregation into Z slices --------------------
// one wave per (rel q, dst d): Z[q*NN+d] = sum of hin[src] rows (bf16)
__global__ __launch_bounds__(256) void agg_k(
    const int* __restrict__ offs, const unsigned short* __restrict__ ssrc,
    const unsigned short* __restrict__ hin, unsigned short* __restrict__ Z) {
  int w = (blockIdx.x * 256 + threadIdx.x) >> 6;
  int lane = threadIdx.x & 63;
  if (w >= NR * NN) return;
  int q = w / NN;
  int d = w - q * NN;
  int lo = offs[d * NR + q];
  int hi = offs[d * NR + q + 1];
  f4_t az = {0.f, 0.f, 0.f, 0.f};
  int e = lo;
  for (; e + 4 <= hi; e += 4) {
    int s0 = ssrc[e], s1 = ssrc[e + 1], s2 = ssrc[e + 2], s3 = ssrc[e + 3];
    ushort4 u0 = *(const ushort4*)(hin + (size_t)s0 * HID + lane * 4);
    ushort4 u1 = *(const ushort4*)(hin + (size_t)s1 * HID + lane * 4);
    ushort4 u2 = *(const ushort4*)(hin + (size_t)s2 * HID + lane * 4);
    ushort4 u3 = *(const ushort4*)(hin + (size_t)s3 * HID + lane * 4);
    az.x += (bf2f(u0.x) + bf2f(u1.x)) + (bf2f(u2.x) + bf2f(u3.x));
    az.y += (bf2f(u0.y) + bf2f(u1.y)) + (bf2f(u2.y) + bf2f(u3.y));
    az.z += (bf2f(u0.z) + bf2f(u1.z)) + (bf2f(u2.z) + bf2f(u3.z));
    az.w += (bf2f(u0.w) + bf2f(u1.w)) + (bf2f(u2.w) + bf2f(u3.w));
  }
  for (; e < hi; ++e) {
    int s = ssrc[e];
    ushort4 u = *(const ushort4*)(hin + (size_t)s * HID + lane * 4);
    az.x += bf2f(u.x); az.y += bf2f(u.y);
    az.z += bf2f(u.z); az.w += bf2f(u.w);
  }
  unsigned short hz[4] = {f2bf(az.x), f2bf(az.y), f2bf(az.z), f2bf(az.w)};
  *(ushort4*)(Z + (size_t)w * HID + lane * 4) = *(ushort4*)hz;
}

// ---------------- layer GEMM halves in ONE launch: grid (625, 2) -----------
// y=0: P0 = self@LWT + sum_{r=0..3} Z_r@W_r ; y=1: P1 = sum_{r=4..7} Z_r@W_r
// block = 32 rows x 256 cols, 8 waves (512 thr); f32 partial out, no bias.
__global__ __launch_bounds__(512) void gemm_part(
    const unsigned short* __restrict__ hbufA,  // self slice [NN][256]
    const unsigned short* __restrict__ Z,      // [NR][NN][256]
    const unsigned short* __restrict__ WT,     // [NR][256][256]
    const unsigned short* __restrict__ LWT,    // [256][256]
    float* __restrict__ P)                     // [2][NN][256]
{
  __shared__ __align__(16) char At[32 * 512];    // 16 KB, swizzled
  __shared__ __align__(16) char Bt[256 * 128];   // 32 KB, swizzled
  const int tid = threadIdx.x;
  const int lane = tid & 63;
  const int w = tid >> 6;        // 0..7
  const int wr = w >> 2;         // 0..1: rows wr*16..+15
  const int wc = w & 3;          // 0..3: cols wc*64..+63
  const int brow = blockIdx.x * 32;
  const int half = blockIdx.y;
  const int sbeg = half ? 5 : 0;
  const int send = half ? 9 : 5;

  f4_t acc[4];
#pragma unroll
  for (int i = 0; i < 4; ++i) acc[i] = (f4_t){0.f, 0.f, 0.f, 0.f};

#pragma unroll 1
  for (int s = sbeg; s < send; ++s) {
    const unsigned short* Asrc = (s == 0) ? hbufA : Z + (size_t)(s - 1) * NN * HID;
    const unsigned short* Wsrc = (s == 0) ? LWT : WT + (size_t)(s - 1) * HID * HID;
    // ---- stage A tile: 32 rows x 256 bf16 (1024 x 16B slots, 2 iters) ----
#pragma unroll
    for (int it = 0; it < 2; ++it) {
      int slot = tid + it * 512;
      int r = slot >> 5, c16 = slot & 31;
      bf8_t v = *(const bf8_t*)(Asrc + (size_t)(brow + r) * HID + c16 * 8);
      *(bf8_t*)(At + r * 512 + ((c16 * 16) ^ ((r & 7) << 4))) = v;
    }
    __syncthreads();
#pragma unroll 1
    for (int kc = 0; kc < 4; ++kc) {
#pragma unroll
      for (int it = 0; it < 4; ++it) {  // stage W chunk: 256 n-rows x 64 k
        int slot = tid + it * 512;
        int n = slot >> 3, c8 = slot & 7;
        bf8_t v = *(const bf8_t*)(Wsrc + (size_t)n * HID + kc * 64 + c8 * 8);
        *(bf8_t*)(Bt + n * 128 + ((c8 * 16) ^ ((n & 7) << 4))) = v;
      }
      __syncthreads();
#pragma unroll
      for (int ks = 0; ks < 2; ++ks) {
        const int kbyte = ks * 64 + (lane >> 4) * 16;
        int m = wr * 16 + (lane & 15);
        bf8_t af = *(const bf8_t*)(
            At + m * 512 + ((kc * 128 + kbyte) ^ ((m & 7) << 4)));
#pragma unroll
        for (int ni = 0; ni < 4; ++ni) {
          int n = wc * 64 + ni * 16 + (lane & 15);
          bf8_t bfr = *(const bf8_t*)(Bt + n * 128 + (kbyte ^ ((n & 7) << 4)));
          acc[ni] = __builtin_amdgcn_mfma_f32_16x16x32_bf16(af, bfr, acc[ni], 0, 0, 0);
        }
      }
      __syncthreads();
    }
  }

  // ---- epilogue: f32 partial; D col = lane&15, row = (lane>>4)*4 + j ----
  float* Pout = P + (size_t)half * NN * HID;
  const int rq = (lane >> 4) * 4;
  const int cl = lane & 15;
#pragma unroll
  for (int ni = 0; ni < 4; ++ni) {
    int c = wc * 64 + ni * 16 + cl;
#pragma unroll
    for (int j = 0; j < 4; ++j) {
      int row = brow + wr * 16 + rq + j;
      Pout[(size_t)row * HID + c] = acc[ni][j];
    }
  }
}

// ---------------- combine: out = P0 + P1 + bias (relu/bf16 for layer 1) ----
template<int RELU>
__global__ __launch_bounds__(256) void combine_k(
    const float* __restrict__ P, const float* __restrict__ bias,
    unsigned short* __restrict__ hb, float* __restrict__ C) {
  int i = blockIdx.x * 256 + threadIdx.x;   // over NN*64 f4 groups
  if (i >= NN * 64) return;
  int row = i >> 6, c4 = (i & 63) * 4;
  size_t o = (size_t)row * HID + c4;
  f4_t a = *(const f4_t*)(P + o);
  f4_t b = *(const f4_t*)(P + (size_t)NN * HID + o);
  f4_t bb = *(const f4_t*)(bias + c4);
  f4_t v = {a.x + b.x + bb.x, a.y + b.y + bb.y,
            a.z + b.z + bb.z, a.w + b.w + bb.w};
  if (RELU) {
    unsigned short h[4] = {f2bf(fmaxf(v.x, 0.f)), f2bf(fmaxf(v.y, 0.f)),
                           f2bf(fmaxf(v.z, 0.f)), f2bf(fmaxf(v.w, 0.f))};
    *(ushort4*)(hb + o) = *(ushort4*)h;
  } else {
    *(f4_t*)(C + o) = v;
  }
}

// ---------------- CSR build: key = dst*NR + etype ----------------
__global__ __launch_bounds__(256) void hist_k(const int* __restrict__ dst,
                                              const int* __restrict__ et,
                                              int* __restrict__ counts) {
  int e = blockIdx.x * 256 + threadIdx.x;
  if (e < NE) atomicAdd(&counts[dst[e] * NR + et[e]], 1);
}

__global__ __launch_bounds__(256) void scan_block(const int* __restrict__ counts,
                                                  int* __restrict__ offs,
                                                  int* __restrict__ bsums) {
  __shared__ int sh[256];
  int base = blockIdx.x * 1024;
  int t = threadIdx.x;
  int v[4];
  int s = 0;
#pragma unroll
  for (int j = 0; j < 4; ++j) {
    int idx = base + t * 4 + j;
    v[j] = (idx < NK) ? counts[idx] : 0;
    s += v[j];
  }
  sh[t] = s;
  __syncthreads();
  for (int off = 1; off < 256; off <<= 1) {
    int x = (t >= off) ? sh[t - off] : 0;
    __syncthreads();
    sh[t] += x;
    __syncthreads();
  }
  int run = sh[t] - s;
#pragma unroll
  for (int j = 0; j < 4; ++j) {
    int idx = base + t * 4 + j;
    if (idx < NK) offs[idx] = run;
    run += v[j];
  }
  if (t == 255) bsums[blockIdx.x] = sh[255];
}

__global__ __launch_bounds__(256) void scan_bsums(int* __restrict__ bsums, int nblk) {
  __shared__ int sh[256];
  int t = threadIdx.x;
  int own = (t < nblk) ? bsums[t] : 0;
  sh[t] = own;
  __syncthreads();
  for (int off = 1; off < 256; off <<= 1) {
    int x = (t >= off) ? sh[t - off] : 0;
    __syncthreads();
    sh[t] += x;
    __syncthreads();
  }
  int ex = sh[t] - own;
  if (t < nblk) bsums[t] = ex;
}

// writes final offs AND cursor copy
__global__ __launch_bounds__(256) void add_base(int* __restrict__ offs,
                                                const int* __restrict__ bsums,
                                                int* __restrict__ cursor) {
  int idx = blockIdx.x * 256 + threadIdx.x;
  if (idx < NK) {
    int v = offs[idx] + bsums[idx >> 10];
    offs[idx] = v;
    cursor[idx] = v;
  }
  if (idx == NK) offs[NK] = NE;
}

__global__ __launch_bounds__(256) void fill_k(const int* __restrict__ src,
                                              const int* __restrict__ dst,
                                              const int* __restrict__ et,
                                              int* __restrict__ cursor,
                                              unsigned short* __restrict__ ssrc) {
  int e = blockIdx.x * 256 + threadIdx.x;
  if (e < NE) {
    int key = dst[e] * NR + et[e];
    int p = atomicAdd(&cursor[key], 1);
    ssrc[p] = (unsigned short)src[e];
  }
}

extern "C" void kernel_launch(void* const* d_in, const int* in_sizes, int n_in,
                              void* d_out, int out_size, void* d_ws, size_t ws_size,
                              hipStream_t stream) {
  const int*   srcp      = (const int*)d_in[0];
  const int*   dstp      = (const int*)d_in[1];
  const int*   etypep    = (const int*)d_in[2];
  const float* poi_dist  = (const float*)d_in[3];
  const float* time_dist = (const float*)d_in[4];
  const float* road_feat = (const float*)d_in[5];
  const float* poi_w     = (const float*)d_in[6];
  const float* poi_b     = (const float*)d_in[7];
  const float* time_w    = (const float*)d_in[8];
  const float* time_b    = (const float*)d_in[9];
  const float* road_w    = (const float*)d_in[10];
  const float* road_b    = (const float*)d_in[11];
  const float* basis1    = (const float*)d_in[12];
  const float* coef1     = (const float*)d_in[13];
  const float* loop_w1   = (const float*)d_in[14];
  const float* bias1     = (const float*)d_in[15];
  const float* basis2    = (const float*)d_in[16];
  const float* coef2     = (const float*)d_in[17];
  const float* loop_w2   = (const float*)d_in[18];
  const float* bias2     = (const float*)d_in[19];

  float* out = (float*)d_out;

  // ws layout (bytes), total ~148.4 MB (ws_size ~921 MB):
  //   WT12 bf16 @ 0           (2,097,152)   [2*NR][256][256] relation W^T
  //   LWT1 bf16 @ 2,097,152   (131,072)
  //   LWT2 bf16 @ 2,228,224   (131,072)
  //   TWT  bf16 @ 2,359,296   (737,280)     time_w^T
  //   hbuf bf16 @ 3,096,576   (10,240,000)  featb in L1; relu(h1) bf16 in L2
  //   Z    bf16 @ 13,336,576  (81,920,000)  8 agg slices (N x 256 each)
  //   TP   f32  @ 95,256,576  (51,200,000)  split-K time partials; P aliases
  //   offs      @ 146,456,576 (640,016)
  //   bsums     @ 147,096,592 (1,024)
  //   ssrc u16  @ 147,097,616 (1,280,000)
  // aliases (each dead before host region's first real write):
  //   counts -> Z;  cursor -> TP;  P(40.96 MB) -> TP (TP dead after time_finish)
  char* ws = (char*)d_ws;
  unsigned short* WT12   = (unsigned short*)(ws);
  unsigned short* LWT1   = (unsigned short*)(ws + 2097152);
  unsigned short* LWT2   = (unsigned short*)(ws + 2228224);
  unsigned short* TWT    = (unsigned short*)(ws + 2359296);
  unsigned short* hbuf   = (unsigned short*)(ws + 3096576);
  unsigned short* Z      = (unsigned short*)(ws + 13336576);
  float*          TP     = (float*)(ws + 95256576);
  int*            offs   = (int*)  (ws + 146456576);
  int*            bsums  = (int*)  (ws + 147096592);
  unsigned short* ssrc   = (unsigned short*)(ws + 147097616);
  int*            counts = (int*)Z;
  int*            cursor = (int*)TP;
  float*          P      = TP;   // reuses TP region after time_finish

  unsigned short* WT1 = WT12;
  unsigned short* WT2 = WT12 + (size_t)NR * HID * HID;

  dim3 blk(256);

  // ---- CSR build ----
  hipMemsetAsync(counts, 0, NK * sizeof(int), stream);
  hist_k<<<NE / 256, blk, 0, stream>>>(dstp, etypep, counts);
  scan_block<<<(NK + 1023) / 1024, blk, 0, stream>>>(counts, offs, bsums);
  scan_bsums<<<1, blk, 0, stream>>>(bsums, (NK + 1023) / 1024);
  add_base<<<(NK + 1 + 255) / 256, blk, 0, stream>>>(offs, bsums, cursor);
  fill_k<<<NE / 256, blk, 0, stream>>>(srcp, dstp, etypep, cursor, ssrc);

  // ---- weight prep (one launch) ----
  prep_k<<<2208, blk, 0, stream>>>(loop_w1, loop_w2, time_w,
                                   coef1, basis1, coef2, basis2,
                                   LWT1, LWT2, TWT, WT12);

  // ---- input projections -> hbuf ----
  proj2_k<<<dim3((NN + 63) / 64, 2), blk, 0, stream>>>(
      poi_dist, poi_w, poi_b, road_feat, road_w, road_b, hbuf);
  mfma_time_sk<<<dim3(NN / 32, SPLITK), blk, 0, stream>>>(time_dist, TWT, TP);
  time_finish<<<(NN * 32 + 255) / 256, blk, 0, stream>>>(TP, time_b, hbuf);

  // ---- layer 1 ----
  agg_k<<<(NR * NN) / 4, blk, 0, stream>>>(offs, ssrc, hbuf, Z);
  gemm_part<<<dim3(NN / 32, 2), 512, 0, stream>>>(hbuf, Z, WT1, LWT1, P);
  combine_k<1><<<(NN * 64 + 255) / 256, blk, 0, stream>>>(P, bias1, hbuf, nullptr);

  // ---- layer 2 ----
  agg_k<<<(NR * NN) / 4, blk, 0, stream>>>(offs, ssrc, hbuf, Z);
  gemm_part<<<dim3(NN / 32, 2), 512, 0, stream>>>(hbuf, Z, WT2, LWT2, P);
  combine_k<0><<<(NN * 64 + 255) / 256, blk, 0, stream>>>(P, bias2, nullptr, out);
}

// Round 10
// 419.744 us; speedup vs baseline: 1.1312x; 1.1009x over previous
//
#include <hip/hip_runtime.h>

#define NN 20000
#define NE 640000
#define NR 8
#define NB 8
#define HID 256
#define KPOI 12
#define KTIME 2880
#define KROAD 128
#define NK (NN * NR)    // 160000 (dst,rel) keys
#define NS 9            // 8 relations + self
#define KCAT (NS * HID) // 2304
#define SPLITK 5
#define KCH (KTIME / SPLITK)   // 576 = 9 x 64

typedef __attribute__((ext_vector_type(8))) short bf8_t;   // 8 bf16 = 4 VGPR
typedef __attribute__((ext_vector_type(4))) float f4_t;

__device__ inline unsigned short f2bf(float f) {  // RNE f32->bf16
  unsigned int u = __float_as_uint(f);
  u += 0x7FFF + ((u >> 16) & 1);
  return (unsigned short)(u >> 16);
}
__device__ inline float bf2f(unsigned short h) {
  return __uint_as_float((unsigned int)h << 16);
}

// ---------------- fused weight prep (all LDS-tiled transposes) --------------
// Builds Wcat_l[o][k] (o=0..255, k=0..2303), k = r*256+i for rels, 2048+i self:
//   blocks [0,256):   basis contraction tiles (16 lr x 16 tiles)
//   blocks [256,288): loop_w transposes into k-rows 2048.. (2 layers x 16)
//   blocks [288,378): time_w transpose tiles (45 x 2)
__global__ __launch_bounds__(256) void prep_k(
    const float* __restrict__ loop_w1, const float* __restrict__ loop_w2,
    const float* __restrict__ time_w,
    const float* __restrict__ coef1, const float* __restrict__ basis1,
    const float* __restrict__ coef2, const float* __restrict__ basis2,
    unsigned short* __restrict__ Wc1, unsigned short* __restrict__ Wc2,
    unsigned short* __restrict__ TWT)
{
  __shared__ unsigned short T[64][66];
  const int b = blockIdx.x;
  const int to = threadIdx.x & 63;
  const int tq = threadIdx.x >> 6;      // 0..3

  if (b < 256) {          // Wc[lr][o][r*256+i] = sum_b coef*basis[b][i][o]
    const int lr = b >> 4;              // 0..15
    const int tile = b & 15;
    const int i0 = ((tile >> 2) & 3) * 64, o0 = (tile & 3) * 64;
    const float* coef  = (lr < NR) ? coef1 : coef2;
    const float* basis = (lr < NR) ? basis1 : basis2;
    unsigned short* Wc = (lr < NR) ? Wc1 : Wc2;
    const int r = lr & 7;
    float cf[NB];
#pragma unroll
    for (int q = 0; q < NB; ++q) cf[q] = coef[r * NB + q];
#pragma unroll
    for (int k = 0; k < 16; ++k) {
      int i_loc = tq * 16 + k;
      int i = i0 + i_loc;
      float acc = 0.f;
#pragma unroll
      for (int q = 0; q < NB; ++q)
        acc += cf[q] * basis[((size_t)(q * HID + i)) * HID + o0 + to];
      T[i_loc][to] = f2bf(acc);
    }
    __syncthreads();
#pragma unroll
    for (int k = 0; k < 16; ++k) {
      int o_loc = tq * 16 + k;
      Wc[(size_t)(o0 + o_loc) * KCAT + r * HID + i0 + to] = T[to][o_loc];
    }
  } else if (b < 288) {   // Wc[l][o][2048+i] = loop_w_l[i][o]
    const int j = b - 256;
    const int layer = j >> 4;
    const int tile = j & 15;
    const int i0 = ((tile >> 2) & 3) * 64, o0 = (tile & 3) * 64;
    const float* lw = layer ? loop_w2 : loop_w1;
    unsigned short* Wc = layer ? Wc2 : Wc1;
#pragma unroll
    for (int k = 0; k < 16; ++k) {
      int i_loc = tq * 16 + k;
      T[i_loc][to] = f2bf(lw[(size_t)(i0 + i_loc) * HID + o0 + to]);
    }
    __syncthreads();
#pragma unroll
    for (int k = 0; k < 16; ++k) {
      int o_loc = tq * 16 + k;
      Wc[(size_t)(o0 + o_loc) * KCAT + NR * HID + i0 + to] = T[to][o_loc];
    }
  } else {                // TWT[c][r] = time_w[r][c], tiled 64x64
    const int j = b - 288;
    const int r0 = (j >> 1) * 64, c0 = (j & 1) * 64;
#pragma unroll
    for (int k = 0; k < 16; ++k) {
      int r_loc = tq * 16 + k;
      T[r_loc][to] = f2bf(time_w[(size_t)(r0 + r_loc) * 128 + c0 + to]);
    }
    __syncthreads();
#pragma unroll
    for (int k = 0; k < 16; ++k) {
      int c_loc = tq * 16 + k;
      TWT[(size_t)(c0 + c_loc) * KTIME + r0 + to] = T[to][c_loc];
    }
  }
}

// ---------------- f32 GEMM tile body (poi/road projections) ----------------
#define BK 16
__device__ inline void sgemm_body(
    int M, int Nn, int K,
    const float* __restrict__ A, int lda,
    const float* __restrict__ B, int ldb,
    const float* __restrict__ bias,
    unsigned short* __restrict__ C, int ldc, int brow)
{
  constexpr int BM = 64, BN = 64, TM = 4, TN = 4;
  constexpr int SA = BM + 4;
  constexpr int SB = BN + 4;
  __shared__ float As[BK * SA];
  __shared__ float Bs[BK * SB];
  const int tid = threadIdx.x;
  constexpr int TCOLS = BN / TN;
  const int row0 = (tid / TCOLS) * TM;
  const int col0 = (tid % TCOLS) * TN;

  float acc[TM][TN] = {};

  for (int kb = 0; kb < K; kb += BK) {
    {
      int i = tid;
      int r = i >> 2, q = (i & 3) * 4;
      int grow = brow + r, gk = kb + q;
      if (grow < M && gk + 3 < K) {
        float4 v = *(const float4*)(A + (size_t)grow * lda + gk);
        As[(q + 0) * SA + r] = v.x;
        As[(q + 1) * SA + r] = v.y;
        As[(q + 2) * SA + r] = v.z;
        As[(q + 3) * SA + r] = v.w;
      } else {
#pragma unroll
        for (int j = 0; j < 4; ++j)
          As[(q + j) * SA + r] =
              (grow < M && gk + j < K) ? A[(size_t)grow * lda + gk + j] : 0.f;
      }
    }
    {
      int i = tid;
      int k = i / (BN / 4), cq = (i % (BN / 4)) * 4;
      int gk = kb + k;
      float4 v = {0.f, 0.f, 0.f, 0.f};
      if (gk < K) {
        if (cq + 3 < Nn) {
          v = *(const float4*)(B + (size_t)gk * ldb + cq);
        } else {
#pragma unroll
          for (int j = 0; j < 4; ++j)
            if (cq + j < Nn) (&v.x)[j] = B[(size_t)gk * ldb + cq + j];
        }
      }
      *(float4*)(&Bs[k * SB + cq]) = v;
    }
    __syncthreads();
#pragma unroll
    for (int kk = 0; kk < BK; ++kk) {
      float a[TM], bb[TN];
      *(float4*)(&a[0]) = *(const float4*)(&As[kk * SA + row0]);
      *(float4*)(&bb[0]) = *(const float4*)(&Bs[kk * SB + col0]);
#pragma unroll
      for (int i = 0; i < TM; ++i)
#pragma unroll
        for (int j = 0; j < TN; ++j)
          acc[i][j] += a[i] * bb[j];
    }
    __syncthreads();
  }

  float bcache[TN];
#pragma unroll
  for (int j = 0; j < TN; ++j) bcache[j] = bias[col0 + j];
#pragma unroll
  for (int i = 0; i < TM; ++i) {
    int row = brow + row0 + i;
    if (row >= M) continue;
#pragma unroll
    for (int j = 0; j < TN; ++j)
      C[(size_t)row * ldc + col0 + j] = f2bf(acc[i][j] + bcache[j]);
  }
}

// poi (y=0) and road (y=1) projections in ONE launch; grid (313, 2)
__global__ __launch_bounds__(256) void proj2_k(
    const float* __restrict__ poi_dist, const float* __restrict__ poi_w,
    const float* __restrict__ poi_b,
    const float* __restrict__ road_feat, const float* __restrict__ road_w,
    const float* __restrict__ road_b,
    unsigned short* __restrict__ hbuf)
{
  const int brow = blockIdx.x * 64;
  if (blockIdx.y == 0)
    sgemm_body(NN, 64, KPOI, poi_dist, KPOI, poi_w, 64, poi_b,
               hbuf + 0, HID, brow);
  else
    sgemm_body(NN, 64, KROAD, road_feat, KROAD, road_w, 64, road_b,
               hbuf + 192, HID, brow);
}

// ---------------- split-K time GEMM: TP[kc] = time_dist[:, kc-chunk] @ TWT^T
__global__ __launch_bounds__(256) void mfma_time_sk(
    const float* __restrict__ A,            // [NN][2880] f32
    const unsigned short* __restrict__ BT,  // [128][2880] bf16
    float* __restrict__ TP)                 // [SPLITK][NN][128]
{
  __shared__ __align__(16) char ldsA[32 * 128];
  __shared__ __align__(16) char ldsB[128 * 128];
  const int tid = threadIdx.x;
  const int lane = tid & 63;
  const int w = tid >> 6;            // 0..3 -> col block w*32
  const int brow = blockIdx.x * 32;
  const int kb0 = blockIdx.y * KCH;

  f4_t acc[2][2];
#pragma unroll
  for (int i = 0; i < 2; ++i)
#pragma unroll
    for (int j = 0; j < 2; ++j) acc[i][j] = (f4_t){0.f, 0.f, 0.f, 0.f};

  for (int kb = kb0; kb < kb0 + KCH; kb += 64) {
    {  // A: 32 rows x 64 k, f32 -> bf16
      int r = tid >> 3, c8 = tid & 7;
      const float* ap = A + (size_t)(brow + r) * KTIME + kb + c8 * 8;
      f4_t v0 = *(const f4_t*)ap;
      f4_t v1 = *(const f4_t*)(ap + 4);
      unsigned short hh[8];
#pragma unroll
      for (int j = 0; j < 4; ++j) { hh[j] = f2bf(v0[j]); hh[4 + j] = f2bf(v1[j]); }
      *(bf8_t*)(ldsA + r * 128 + ((c8 * 16) ^ ((r & 7) << 4))) = *(bf8_t*)hh;
    }
#pragma unroll
    for (int it = 0; it < 4; ++it) {  // B: 128 rows x 64 k
      int slot = tid + it * 256;
      int r = slot >> 3, c8 = slot & 7;
      bf8_t v = *(const bf8_t*)(BT + (size_t)r * KTIME + kb + c8 * 8);
      *(bf8_t*)(ldsB + r * 128 + ((c8 * 16) ^ ((r & 7) << 4))) = v;
    }
    __syncthreads();
#pragma unroll
    for (int ks = 0; ks < 2; ++ks) {
      const int kbyte = ks * 64 + (lane >> 4) * 16;
      bf8_t af[2], bfr[2];
#pragma unroll
      for (int mi = 0; mi < 2; ++mi) {
        int m = mi * 16 + (lane & 15);
        af[mi] = *(const bf8_t*)(ldsA + m * 128 + (kbyte ^ ((m & 7) << 4)));
      }
#pragma unroll
      for (int ni = 0; ni < 2; ++ni) {
        int n = w * 32 + ni * 16 + (lane & 15);
        bfr[ni] = *(const bf8_t*)(ldsB + n * 128 + (kbyte ^ ((n & 7) << 4)));
      }
#pragma unroll
      for (int mi = 0; mi < 2; ++mi)
#pragma unroll
        for (int ni = 0; ni < 2; ++ni)
          acc[mi][ni] = __builtin_amdgcn_mfma_f32_16x16x32_bf16(
              af[mi], bfr[ni], acc[mi][ni], 0, 0, 0);
    }
    __syncthreads();
  }

  float* tp = TP + (size_t)blockIdx.y * NN * 128;
  const int rq = (lane >> 4) * 4;
  const int cl = lane & 15;
#pragma unroll
  for (int ni = 0; ni < 2; ++ni) {
    int c = w * 32 + ni * 16 + cl;
#pragma unroll
    for (int mi = 0; mi < 2; ++mi) {
#pragma unroll
      for (int j = 0; j < 4; ++j) {
        int row = brow + mi * 16 + rq + j;
        tp[(size_t)row * 128 + c] = acc[mi][ni][j];
      }
    }
  }
}

// ---------------- time finish: hbuf[:,64:192] = bf16(sum_k TP + bias) ------
__global__ __launch_bounds__(256) void time_finish(
    const float* __restrict__ TP, const float* __restrict__ bias,
    unsigned short* __restrict__ featb) {
  int i = blockIdx.x * 256 + threadIdx.x;   // over NN*32 float4 groups
  if (i >= NN * 32) return;
  int row = i >> 5, c4 = (i & 31) * 4;
  f4_t s = *(const f4_t*)(TP + (size_t)row * 128 + c4);
#pragma unroll
  for (int k = 1; k < SPLITK; ++k) {
    f4_t v = *(const f4_t*)(TP + (size_t)k * NN * 128 + (size_t)row * 128 + c4);
    s.x += v.x; s.y += v.y; s.z += v.z; s.w += v.w;
  }
  f4_t b = *(const f4_t*)(bias + c4);
  unsigned short h[4] = {f2bf(s.x + b.x), f2bf(s.y + b.y),
                         f2bf(s.z + b.z), f2bf(s.w + b.w)};
  *(ushort4*)(featb + (size_t)row * 256 + 64 + c4) = *(ushort4*)h;
}

// ---------------- CSR aggregation into Zcat [NN][KCAT] ---------------------
// one wave per (slice q, dst d): Zcat[d][q*256+..] = sum of hin[src] rows;
// q == 8 is the self slice (copy of hin[d]).
__global__ __launch_bounds__(256) void agg_k(
    const int* __restrict__ offs, const unsigned short* __restrict__ ssrc,
    const unsigned short* __restrict__ hin, unsigned short* __restrict__ Zc) {
  int w = (blockIdx.x * 256 + threadIdx.x) >> 6;
  int lane = threadIdx.x & 63;
  if (w >= NS * NN) return;
  int q = w / NN;
  int d = w - q * NN;
  unsigned short* zp = Zc + (size_t)d * KCAT + q * HID + lane * 4;
  if (q == NR) {   // self slice: copy
    *(ushort4*)zp = *(const ushort4*)(hin + (size_t)d * HID + lane * 4);
    return;
  }
  int lo = offs[d * NR + q];
  int hi = offs[d * NR + q + 1];
  f4_t az = {0.f, 0.f, 0.f, 0.f};
  int e = lo;
  for (; e + 4 <= hi; e += 4) {
    int s0 = ssrc[e], s1 = ssrc[e + 1], s2 = ssrc[e + 2], s3 = ssrc[e + 3];
    ushort4 u0 = *(const ushort4*)(hin + (size_t)s0 * HID + lane * 4);
    ushort4 u1 = *(const ushort4*)(hin + (size_t)s1 * HID + lane * 4);
    ushort4 u2 = *(const ushort4*)(hin + (size_t)s2 * HID + lane * 4);
    ushort4 u3 = *(const ushort4*)(hin + (size_t)s3 * HID + lane * 4);
    az.x += (bf2f(u0.x) + bf2f(u1.x)) + (bf2f(u2.x) + bf2f(u3.x));
    az.y += (bf2f(u0.y) + bf2f(u1.y)) + (bf2f(u2.y) + bf2f(u3.y));
    az.z += (bf2f(u0.z) + bf2f(u1.z)) + (bf2f(u2.z) + bf2f(u3.z));
    az.w += (bf2f(u0.w) + bf2f(u1.w)) + (bf2f(u2.w) + bf2f(u3.w));
  }
  for (; e < hi; ++e) {
    int s = ssrc[e];
    ushort4 u = *(const ushort4*)(hin + (size_t)s * HID + lane * 4);
    az.x += bf2f(u.x); az.y += bf2f(u.y);
    az.z += bf2f(u.z); az.w += bf2f(u.w);
  }
  unsigned short hz[4] = {f2bf(az.x), f2bf(az.y), f2bf(az.z), f2bf(az.w)};
  *(ushort4*)zp = *(ushort4*)hz;
}

// ---------------- layer GEMM: C[64x256] = Zcat @ Wcat + bias ---------------
// K = 2304 single loop; 8 waves (2m x 4n), wave = 32 rows x 64 cols.
// EPI 0: C = f32. EPI 1: hb = bf16(relu(.)).
template<int EPI>
__global__ __launch_bounds__(512) void gemm_cat(
    const unsigned short* __restrict__ Zc,    // [NN][KCAT]
    const unsigned short* __restrict__ Wc,    // [256][KCAT]
    const float* __restrict__ bias,
    float* __restrict__ C, unsigned short* __restrict__ hb)
{
  __shared__ __align__(16) char At[64 * 128];    // 8 KB  (64 rows x 64k)
  __shared__ __align__(16) char Bt[256 * 128];   // 32 KB (256 o-rows x 64k)
  const int tid = threadIdx.x;
  const int lane = tid & 63;
  const int w = tid >> 6;        // 0..7
  const int wm = w >> 2;         // 0..1: rows wm*32..+31
  const int wn = w & 3;          // 0..3: cols wn*64..+63
  const int brow = blockIdx.x * 64;

  f4_t acc[2][4];
#pragma unroll
  for (int i = 0; i < 2; ++i)
#pragma unroll
    for (int j = 0; j < 4; ++j) acc[i][j] = (f4_t){0.f, 0.f, 0.f, 0.f};

  for (int kb = 0; kb < KCAT; kb += 64) {
    {  // stage A: 64 rows x 64 k (512 thr x 16B = 8 KB exactly)
      int r = tid >> 3, c8 = tid & 7;
      int grow = brow + r;
      bf8_t v = {0, 0, 0, 0, 0, 0, 0, 0};
      if (grow < NN) v = *(const bf8_t*)(Zc + (size_t)grow * KCAT + kb + c8 * 8);
      *(bf8_t*)(At + r * 128 + ((c8 * 16) ^ ((r & 7) << 4))) = v;
    }
#pragma unroll
    for (int it = 0; it < 4; ++it) {  // stage B: 256 o-rows x 64 k
      int slot = tid + it * 512;
      int n = slot >> 3, c8 = slot & 7;
      bf8_t v = *(const bf8_t*)(Wc + (size_t)n * KCAT + kb + c8 * 8);
      *(bf8_t*)(Bt + n * 128 + ((c8 * 16) ^ ((n & 7) << 4))) = v;
    }
    __syncthreads();
#pragma unroll
    for (int ks = 0; ks < 2; ++ks) {
      const int kbyte = ks * 64 + (lane >> 4) * 16;
      bf8_t af[2], bfr[4];
#pragma unroll
      for (int mi = 0; mi < 2; ++mi) {
        int m = wm * 32 + mi * 16 + (lane & 15);
        af[mi] = *(const bf8_t*)(At + m * 128 + (kbyte ^ ((m & 7) << 4)));
      }
#pragma unroll
      for (int ni = 0; ni < 4; ++ni) {
        int n = wn * 64 + ni * 16 + (lane & 15);
        bfr[ni] = *(const bf8_t*)(Bt + n * 128 + (kbyte ^ ((n & 7) << 4)));
      }
#pragma unroll
      for (int mi = 0; mi < 2; ++mi)
#pragma unroll
        for (int ni = 0; ni < 4; ++ni)
          acc[mi][ni] = __builtin_amdgcn_mfma_f32_16x16x32_bf16(
              af[mi], bfr[ni], acc[mi][ni], 0, 0, 0);
    }
    __syncthreads();
  }

  // ---- epilogue: D col = lane&15, row = (lane>>4)*4 + j ----
  const int rq = (lane >> 4) * 4;
  const int cl = lane & 15;
#pragma unroll
  for (int ni = 0; ni < 4; ++ni) {
    int c = wn * 64 + ni * 16 + cl;
    float bv = bias[c];
#pragma unroll
    for (int mi = 0; mi < 2; ++mi) {
#pragma unroll
      for (int j = 0; j < 4; ++j) {
        int row = brow + wm * 32 + mi * 16 + rq + j;
        if (row < NN) {
          size_t o = (size_t)row * HID + c;
          float v = acc[mi][ni][j] + bv;
          if (EPI == 0) C[o] = v;
          else          hb[o] = f2bf(fmaxf(v, 0.f));
        }
      }
    }
  }
}

// ---------------- CSR build: key = dst*NR + etype ----------------
__global__ __launch_bounds__(256) void hist_k(const int* __restrict__ dst,
                                              const int* __restrict__ et,
                                              int* __restrict__ counts) {
  int e = blockIdx.x * 256 + threadIdx.x;
  if (e < NE) atomicAdd(&counts[dst[e] * NR + et[e]], 1);
}

__global__ __launch_bounds__(256) void scan_block(const int* __restrict__ counts,
                                                  int* __restrict__ offs,
                                                  int* __restrict__ bsums) {
  __shared__ int sh[256];
  int base = blockIdx.x * 1024;
  int t = threadIdx.x;
  int v[4];
  int s = 0;
#pragma unroll
  for (int j = 0; j < 4; ++j) {
    int idx = base + t * 4 + j;
    v[j] = (idx < NK) ? counts[idx] : 0;
    s += v[j];
  }
  sh[t] = s;
  __syncthreads();
  for (int off = 1; off < 256; off <<= 1) {
    int x = (t >= off) ? sh[t - off] : 0;
    __syncthreads();
    sh[t] += x;
    __syncthreads();
  }
  int run = sh[t] - s;
#pragma unroll
  for (int j = 0; j < 4; ++j) {
    int idx = base + t * 4 + j;
    if (idx < NK) offs[idx] = run;
    run += v[j];
  }
  if (t == 255) bsums[blockIdx.x] = sh[255];
}

__global__ __launch_bounds__(256) void scan_bsums(int* __restrict__ bsums, int nblk) {
  __shared__ int sh[256];
  int t = threadIdx.x;
  int own = (t < nblk) ? bsums[t] : 0;
  sh[t] = own;
  __syncthreads();
  for (int off = 1; off < 256; off <<= 1) {
    int x = (t >= off) ? sh[t - off] : 0;
    __syncthreads();
    sh[t] += x;
    __syncthreads();
  }
  int ex = sh[t] - own;
  if (t < nblk) bsums[t] = ex;
}

// writes final offs AND cursor copy
__global__ __launch_bounds__(256) void add_base(int* __restrict__ offs,
                                                const int* __restrict__ bsums,
                                                int* __restrict__ cursor) {
  int idx = blockIdx.x * 256 + threadIdx.x;
  if (idx < NK) {
    int v = offs[idx] + bsums[idx >> 10];
    offs[idx] = v;
    cursor[idx] = v;
  }
  if (idx == NK) offs[NK] = NE;
}

__global__ __launch_bounds__(256) void fill_k(const int* __restrict__ src,
                                              const int* __restrict__ dst,
                                              const int* __restrict__ et,
                                              int* __restrict__ cursor,
                                              unsigned short* __restrict__ ssrc) {
  int e = blockIdx.x * 256 + threadIdx.x;
  if (e < NE) {
    int key = dst[e] * NR + et[e];
    int p = atomicAdd(&cursor[key], 1);
    ssrc[p] = (unsigned short)src[e];
  }
}

extern "C" void kernel_launch(void* const* d_in, const int* in_sizes, int n_in,
                              void* d_out, int out_size, void* d_ws, size_t ws_size,
                              hipStream_t stream) {
  const int*   srcp      = (const int*)d_in[0];
  const int*   dstp      = (const int*)d_in[1];
  const int*   etypep    = (const int*)d_in[2];
  const float* poi_dist  = (const float*)d_in[3];
  const float* time_dist = (const float*)d_in[4];
  const float* road_feat = (const float*)d_in[5];
  const float* poi_w     = (const float*)d_in[6];
  const float* poi_b     = (const float*)d_in[7];
  const float* time_w    = (const float*)d_in[8];
  const float* time_b    = (const float*)d_in[9];
  const float* road_w    = (const float*)d_in[10];
  const float* road_b    = (const float*)d_in[11];
  const float* basis1    = (const float*)d_in[12];
  const float* coef1     = (const float*)d_in[13];
  const float* loop_w1   = (const float*)d_in[14];
  const float* bias1     = (const float*)d_in[15];
  const float* basis2    = (const float*)d_in[16];
  const float* coef2     = (const float*)d_in[17];
  const float* loop_w2   = (const float*)d_in[18];
  const float* bias2     = (const float*)d_in[19];

  float* out = (float*)d_out;

  // ws layout (bytes), total ~160 MB (ws_size ~921 MB):
  //   Wc1  bf16 @ 0           (1,179,648)   [256][2304] layer-1 cat weights
  //   Wc2  bf16 @ 1,179,648   (1,179,648)
  //   TWT  bf16 @ 2,359,296   (737,280)     time_w^T
  //   hbuf bf16 @ 3,096,576   (10,240,000)  feat; then relu(h1) bf16
  //   Zcat bf16 @ 13,336,576  (92,160,000)  [NN][2304] agg+self slices
  //   TP   f32  @ 105,496,576 (51,200,000)  split-K time partials
  //   offs      @ 156,696,576 (640,016)
  //   bsums     @ 157,336,592 (1,024)
  //   ssrc u16  @ 157,337,616 (1,280,000)
  // aliases (dead before host region's first real write):
  //   counts -> Zcat;  cursor -> TP
  char* ws = (char*)d_ws;
  unsigned short* Wc1    = (unsigned short*)(ws);
  unsigned short* Wc2    = (unsigned short*)(ws + 1179648);
  unsigned short* TWT    = (unsigned short*)(ws + 2359296);
  unsigned short* hbuf   = (unsigned short*)(ws + 3096576);
  unsigned short* Zcat   = (unsigned short*)(ws + 13336576);
  float*          TP     = (float*)(ws + 105496576);
  int*            offs   = (int*)  (ws + 156696576);
  int*            bsums  = (int*)  (ws + 157336592);
  unsigned short* ssrc   = (unsigned short*)(ws + 157337616);
  int*            counts = (int*)Zcat;
  int*            cursor = (int*)TP;

  dim3 blk(256);

  // ---- CSR build ----
  hipMemsetAsync(counts, 0, NK * sizeof(int), stream);
  hist_k<<<NE / 256, blk, 0, stream>>>(dstp, etypep, counts);
  scan_block<<<(NK + 1023) / 1024, blk, 0, stream>>>(counts, offs, bsums);
  scan_bsums<<<1, blk, 0, stream>>>(bsums, (NK + 1023) / 1024);
  add_base<<<(NK + 1 + 255) / 256, blk, 0, stream>>>(offs, bsums, cursor);
  fill_k<<<NE / 256, blk, 0, stream>>>(srcp, dstp, etypep, cursor, ssrc);

  // ---- weight prep (one launch, 378 tiled blocks) ----
  prep_k<<<378, blk, 0, stream>>>(loop_w1, loop_w2, time_w,
                                  coef1, basis1, coef2, basis2,
                                  Wc1, Wc2, TWT);

  // ---- input projections -> hbuf ----
  proj2_k<<<dim3((NN + 63) / 64, 2), blk, 0, stream>>>(
      poi_dist, poi_w, poi_b, road_feat, road_w, road_b, hbuf);
  mfma_time_sk<<<dim3(NN / 32, SPLITK), blk, 0, stream>>>(time_dist, TWT, TP);
  time_finish<<<(NN * 32 + 255) / 256, blk, 0, stream>>>(TP, time_b, hbuf);

  // ---- layer 1: Zcat = agg(hbuf); hbuf = bf16(relu(Zcat @ Wc1 + b1)) ----
  agg_k<<<(NS * NN + 3) / 4, blk, 0, stream>>>(offs, ssrc, hbuf, Zcat);
  gemm_cat<1><<<(NN + 63) / 64, 512, 0, stream>>>(Zcat, Wc1, bias1, nullptr, hbuf);

  // ---- layer 2: Zcat = agg(hbuf); out = Zcat @ Wc2 + b2 (f32) ----
  agg_k<<<(NS * NN + 3) / 4, blk, 0, stream>>>(offs, ssrc, hbuf, Zcat);
  gemm_cat<0><<<(NN + 63) / 64, 512, 0, stream>>>(Zcat, Wc2, bias2, out, nullptr);
}

// Round 11
// 399.539 us; speedup vs baseline: 1.1884x; 1.0506x over previous
//
#include <hip/hip_runtime.h>

#define NN 20000
#define NE 640000
#define NR 8
#define NB 8
#define HID 256
#define KPOI 12
#define KTIME 2880
#define KROAD 128
#define NK (NN * NR)    // 160000 (dst,rel) keys
#define NS 9            // 8 relations + self
#define KCAT (NS * HID) // 2304

typedef __attribute__((ext_vector_type(8))) short bf8_t;   // 8 bf16 = 4 VGPR
typedef __attribute__((ext_vector_type(4))) float f4_t;

__device__ inline unsigned short f2bf(float f) {  // RNE f32->bf16
  unsigned int u = __float_as_uint(f);
  u += 0x7FFF + ((u >> 16) & 1);
  return (unsigned short)(u >> 16);
}
__device__ inline float bf2f(unsigned short h) {
  return __uint_as_float((unsigned int)h << 16);
}

// ---------------- f32 GEMM tile body (poi/road projections) ----------------
#define BK 16
__device__ inline void sgemm_body(
    int M, int Nn, int K,
    const float* __restrict__ A, int lda,
    const float* __restrict__ B, int ldb,
    const float* __restrict__ bias,
    unsigned short* __restrict__ C, int ldc, int brow, char* lds)
{
  constexpr int BM = 64, BN = 64, TM = 4, TN = 4;
  constexpr int SA = BM + 4;
  constexpr int SB = BN + 4;
  float* As = (float*)lds;                  // BK*SA = 1088 f32 = 4352 B
  float* Bs = (float*)(lds + 4352);         // BK*SB = 4352 B
  const int tid = threadIdx.x;
  constexpr int TCOLS = BN / TN;
  const int row0 = (tid / TCOLS) * TM;
  const int col0 = (tid % TCOLS) * TN;

  float acc[TM][TN] = {};

  for (int kb = 0; kb < K; kb += BK) {
    {
      int i = tid;
      int r = i >> 2, q = (i & 3) * 4;
      int grow = brow + r, gk = kb + q;
      if (grow < M && gk + 3 < K) {
        float4 v = *(const float4*)(A + (size_t)grow * lda + gk);
        As[(q + 0) * SA + r] = v.x;
        As[(q + 1) * SA + r] = v.y;
        As[(q + 2) * SA + r] = v.z;
        As[(q + 3) * SA + r] = v.w;
      } else {
#pragma unroll
        for (int j = 0; j < 4; ++j)
          As[(q + j) * SA + r] =
              (grow < M && gk + j < K) ? A[(size_t)grow * lda + gk + j] : 0.f;
      }
    }
    {
      int i = tid;
      int k = i / (BN / 4), cq = (i % (BN / 4)) * 4;
      int gk = kb + k;
      float4 v = {0.f, 0.f, 0.f, 0.f};
      if (gk < K) {
        if (cq + 3 < Nn) {
          v = *(const float4*)(B + (size_t)gk * ldb + cq);
        } else {
#pragma unroll
          for (int j = 0; j < 4; ++j)
            if (cq + j < Nn) (&v.x)[j] = B[(size_t)gk * ldb + cq + j];
        }
      }
      *(float4*)(&Bs[k * SB + cq]) = v;
    }
    __syncthreads();
#pragma unroll
    for (int kk = 0; kk < BK; ++kk) {
      float a[TM], bb[TN];
      *(float4*)(&a[0]) = *(const float4*)(&As[kk * SA + row0]);
      *(float4*)(&bb[0]) = *(const float4*)(&Bs[kk * SB + col0]);
#pragma unroll
      for (int i = 0; i < TM; ++i)
#pragma unroll
        for (int j = 0; j < TN; ++j)
          acc[i][j] += a[i] * bb[j];
    }
    __syncthreads();
  }

  float bcache[TN];
#pragma unroll
  for (int j = 0; j < TN; ++j) bcache[j] = bias[col0 + j];
#pragma unroll
  for (int i = 0; i < TM; ++i) {
    int row = brow + row0 + i;
    if (row >= M) continue;
#pragma unroll
    for (int j = 0; j < TN; ++j)
      C[(size_t)row * ldc + col0 + j] = f2bf(acc[i][j] + bcache[j]);
  }
}

// ---------------- fused prep + projections (one launch, 1004 blocks) -------
// [0,256):   Wcat basis-contraction tiles  [256,288): loop_w transposes
// [288,378): time_w transpose tiles        [378,691): poi GEMM
// [691,1004): road GEMM
__global__ __launch_bounds__(256) void prep_proj_k(
    const float* __restrict__ loop_w1, const float* __restrict__ loop_w2,
    const float* __restrict__ time_w,
    const float* __restrict__ coef1, const float* __restrict__ basis1,
    const float* __restrict__ coef2, const float* __restrict__ basis2,
    const float* __restrict__ poi_dist, const float* __restrict__ poi_w,
    const float* __restrict__ poi_b,
    const float* __restrict__ road_feat, const float* __restrict__ road_w,
    const float* __restrict__ road_b,
    unsigned short* __restrict__ Wc1, unsigned short* __restrict__ Wc2,
    unsigned short* __restrict__ TWT, unsigned short* __restrict__ hbuf)
{
  __shared__ __align__(16) char lds[8704];
  const int b = blockIdx.x;
  const int to = threadIdx.x & 63;
  const int tq = threadIdx.x >> 6;

  if (b < 378) {
    unsigned short (*T)[66] = (unsigned short (*)[66])lds;
    if (b < 256) {        // Wc[lr][o][r*256+i] = sum_q coef*basis[q][i][o]
      const int lr = b >> 4;
      const int tile = b & 15;
      const int i0 = ((tile >> 2) & 3) * 64, o0 = (tile & 3) * 64;
      const float* coef  = (lr < NR) ? coef1 : coef2;
      const float* basis = (lr < NR) ? basis1 : basis2;
      unsigned short* Wc = (lr < NR) ? Wc1 : Wc2;
      const int r = lr & 7;
      float cf[NB];
#pragma unroll
      for (int q = 0; q < NB; ++q) cf[q] = coef[r * NB + q];
#pragma unroll
      for (int k = 0; k < 16; ++k) {
        int i_loc = tq * 16 + k;
        int i = i0 + i_loc;
        float acc = 0.f;
#pragma unroll
        for (int q = 0; q < NB; ++q)
          acc += cf[q] * basis[((size_t)(q * HID + i)) * HID + o0 + to];
        T[i_loc][to] = f2bf(acc);
      }
      __syncthreads();
#pragma unroll
      for (int k = 0; k < 16; ++k) {
        int o_loc = tq * 16 + k;
        Wc[(size_t)(o0 + o_loc) * KCAT + r * HID + i0 + to] = T[to][o_loc];
      }
    } else if (b < 288) { // Wc[l][o][2048+i] = loop_w_l[i][o]
      const int j = b - 256;
      const int layer = j >> 4;
      const int tile = j & 15;
      const int i0 = ((tile >> 2) & 3) * 64, o0 = (tile & 3) * 64;
      const float* lw = layer ? loop_w2 : loop_w1;
      unsigned short* Wc = layer ? Wc2 : Wc1;
#pragma unroll
      for (int k = 0; k < 16; ++k) {
        int i_loc = tq * 16 + k;
        T[i_loc][to] = f2bf(lw[(size_t)(i0 + i_loc) * HID + o0 + to]);
      }
      __syncthreads();
#pragma unroll
      for (int k = 0; k < 16; ++k) {
        int o_loc = tq * 16 + k;
        Wc[(size_t)(o0 + o_loc) * KCAT + NR * HID + i0 + to] = T[to][o_loc];
      }
    } else {              // TWT[c][r] = time_w[r][c], tiled 64x64
      const int j = b - 288;
      const int r0 = (j >> 1) * 64, c0 = (j & 1) * 64;
#pragma unroll
      for (int k = 0; k < 16; ++k) {
        int r_loc = tq * 16 + k;
        T[r_loc][to] = f2bf(time_w[(size_t)(r0 + r_loc) * 128 + c0 + to]);
      }
      __syncthreads();
#pragma unroll
      for (int k = 0; k < 16; ++k) {
        int c_loc = tq * 16 + k;
        TWT[(size_t)(c0 + c_loc) * KTIME + r0 + to] = T[to][c_loc];
      }
    }
  } else if (b < 691) {   // poi projection -> hbuf cols [0,64)
    sgemm_body(NN, 64, KPOI, poi_dist, KPOI, poi_w, 64, poi_b,
               hbuf + 0, HID, (b - 378) * 64, lds);
  } else {                // road projection -> hbuf cols [192,256)
    sgemm_body(NN, 64, KROAD, road_feat, KROAD, road_w, 64, road_b,
               hbuf + 192, HID, (b - 691) * 64, lds);
  }
}

// ---------------- time GEMM, in-block split-K -------------------------------
// 625 blocks x 512 thr (8 waves = 4 col-blocks x 2 K-groups of 23/22 steps).
// Group-1 partials LDS-reduced into group-0; epilogue writes bf16 + bias.
__global__ __launch_bounds__(512) void mfma_time2(
    const float* __restrict__ A,            // [NN][2880] f32
    const unsigned short* __restrict__ BT,  // [128][2880] bf16
    const float* __restrict__ bias,         // [128]
    unsigned short* __restrict__ featb)     // [NN][256], cols 64..191
{
  __shared__ __align__(16) char ldsA[2 * 32 * 128];    // 8 KB  [g][r][128B]
  __shared__ __align__(16) char ldsB[2 * 128 * 128];   // 32 KB [g][n][128B]
  const int tid = threadIdx.x;
  const int lane = tid & 63;
  const int w = tid >> 6;        // 0..7
  const int g = w >> 2;          // K-group
  const int cb = w & 3;          // col block (32 cols)
  const int brow = blockIdx.x * 32;

  f4_t acc[2][2];
#pragma unroll
  for (int i = 0; i < 2; ++i)
#pragma unroll
    for (int j = 0; j < 2; ++j) acc[i][j] = (f4_t){0.f, 0.f, 0.f, 0.f};

  for (int i = 0; i < 23; ++i) {
    {  // stage A: 512 slots (2 groups x 32 rows x 8 c8), f32 -> bf16
      int sg = tid >> 8, r = (tid >> 3) & 31, c8 = tid & 7;
      int step = sg * 23 + i;
      unsigned short hh[8] = {0, 0, 0, 0, 0, 0, 0, 0};
      if (step < 45) {
        const float* ap = A + (size_t)(brow + r) * KTIME + step * 64 + c8 * 8;
        f4_t v0 = *(const f4_t*)ap;
        f4_t v1 = *(const f4_t*)(ap + 4);
#pragma unroll
        for (int j = 0; j < 4; ++j) { hh[j] = f2bf(v0[j]); hh[4 + j] = f2bf(v1[j]); }
      }
      *(bf8_t*)(ldsA + sg * 4096 + r * 128 + ((c8 * 16) ^ ((r & 7) << 4))) =
          *(bf8_t*)hh;
    }
#pragma unroll
    for (int it = 0; it < 4; ++it) {  // stage B: 2048 slots (2 g x 128 n x 8)
      int s = tid + it * 512;
      int sg = s >> 10, r = (s >> 3) & 127, c8 = s & 7;
      int step = sg * 23 + i;
      bf8_t v = {0, 0, 0, 0, 0, 0, 0, 0};
      if (step < 45)
        v = *(const bf8_t*)(BT + (size_t)r * KTIME + step * 64 + c8 * 8);
      *(bf8_t*)(ldsB + sg * 16384 + r * 128 + ((c8 * 16) ^ ((r & 7) << 4))) = v;
    }
    __syncthreads();
    if (g * 23 + i < 45) {
#pragma unroll
      for (int ks = 0; ks < 2; ++ks) {
        const int kbyte = ks * 64 + (lane >> 4) * 16;
        bf8_t af[2], bfr[2];
#pragma unroll
        for (int mi = 0; mi < 2; ++mi) {
          int m = mi * 16 + (lane & 15);
          af[mi] = *(const bf8_t*)(
              ldsA + g * 4096 + m * 128 + (kbyte ^ ((m & 7) << 4)));
        }
#pragma unroll
        for (int ni = 0; ni < 2; ++ni) {
          int n = cb * 32 + ni * 16 + (lane & 15);
          bfr[ni] = *(const bf8_t*)(
              ldsB + g * 16384 + n * 128 + (kbyte ^ ((n & 7) << 4)));
        }
#pragma unroll
        for (int mi = 0; mi < 2; ++mi)
#pragma unroll
          for (int ni = 0; ni < 2; ++ni)
            acc[mi][ni] = __builtin_amdgcn_mfma_f32_16x16x32_bf16(
                af[mi], bfr[ni], acc[mi][ni], 0, 0, 0);
      }
    }
    __syncthreads();
  }

  // ---- cross-group reduce via LDS (reuse ldsB region: 16 KB needed) ----
  float* rb = (float*)ldsB;
  if (g == 1) {
#pragma unroll
    for (int mi = 0; mi < 2; ++mi)
#pragma unroll
      for (int ni = 0; ni < 2; ++ni)
#pragma unroll
        for (int j = 0; j < 4; ++j)
          rb[(cb * 64 + lane) * 16 + (mi * 2 + ni) * 4 + j] = acc[mi][ni][j];
  }
  __syncthreads();
  if (g == 0) {
    const int rq = (lane >> 4) * 4;
    const int cl = lane & 15;
#pragma unroll
    for (int ni = 0; ni < 2; ++ni) {
      int c = cb * 32 + ni * 16 + cl;
      float bv = bias[c];
#pragma unroll
      for (int mi = 0; mi < 2; ++mi) {
#pragma unroll
        for (int j = 0; j < 4; ++j) {
          float v = acc[mi][ni][j] +
                    rb[(cb * 64 + lane) * 16 + (mi * 2 + ni) * 4 + j] + bv;
          int row = brow + mi * 16 + rq + j;   // < 20000 always
          featb[(size_t)row * 256 + 64 + c] = f2bf(v);
        }
      }
    }
  }
}

// ---------------- CSR aggregation: one wave per dst, all 9 slices ----------
__global__ __launch_bounds__(256) void agg_k(
    const int* __restrict__ offs, const unsigned short* __restrict__ ssrc,
    const unsigned short* __restrict__ hin, unsigned short* __restrict__ Zc) {
  int d = (blockIdx.x * 256 + threadIdx.x) >> 6;
  int lane = threadIdx.x & 63;
  if (d >= NN) return;
  unsigned short* zrow = Zc + (size_t)d * KCAT;
  // self slice
  *(ushort4*)(zrow + NR * HID + lane * 4) =
      *(const ushort4*)(hin + (size_t)d * HID + lane * 4);
  int ob[NR + 1];
#pragma unroll
  for (int r = 0; r <= NR; ++r) ob[r] = offs[d * NR + r];
#pragma unroll 1
  for (int q = 0; q < NR; ++q) {
    int e = ob[q], hi = ob[q + 1];
    f4_t az = {0.f, 0.f, 0.f, 0.f};
    for (; e + 4 <= hi; e += 4) {
      int s0 = ssrc[e], s1 = ssrc[e + 1], s2 = ssrc[e + 2], s3 = ssrc[e + 3];
      ushort4 u0 = *(const ushort4*)(hin + (size_t)s0 * HID + lane * 4);
      ushort4 u1 = *(const ushort4*)(hin + (size_t)s1 * HID + lane * 4);
      ushort4 u2 = *(const ushort4*)(hin + (size_t)s2 * HID + lane * 4);
      ushort4 u3 = *(const ushort4*)(hin + (size_t)s3 * HID + lane * 4);
      az.x += (bf2f(u0.x) + bf2f(u1.x)) + (bf2f(u2.x) + bf2f(u3.x));
      az.y += (bf2f(u0.y) + bf2f(u1.y)) + (bf2f(u2.y) + bf2f(u3.y));
      az.z += (bf2f(u0.z) + bf2f(u1.z)) + (bf2f(u2.z) + bf2f(u3.z));
      az.w += (bf2f(u0.w) + bf2f(u1.w)) + (bf2f(u2.w) + bf2f(u3.w));
    }
    for (; e < hi; ++e) {
      int s = ssrc[e];
      ushort4 u = *(const ushort4*)(hin + (size_t)s * HID + lane * 4);
      az.x += bf2f(u.x); az.y += bf2f(u.y);
      az.z += bf2f(u.z); az.w += bf2f(u.w);
    }
    unsigned short hz[4] = {f2bf(az.x), f2bf(az.y), f2bf(az.z), f2bf(az.w)};
    *(ushort4*)(zrow + q * HID + lane * 4) = *(ushort4*)hz;
  }
}

// ---------------- layer GEMM: C[64x256] = Zcat @ Wcat + bias ---------------
template<int EPI>
__global__ __launch_bounds__(512) void gemm_cat(
    const unsigned short* __restrict__ Zc,    // [NN][KCAT]
    const unsigned short* __restrict__ Wc,    // [256][KCAT]
    const float* __restrict__ bias,
    float* __restrict__ C, unsigned short* __restrict__ hb)
{
  __shared__ __align__(16) char At[64 * 128];    // 8 KB
  __shared__ __align__(16) char Bt[256 * 128];   // 32 KB
  const int tid = threadIdx.x;
  const int lane = tid & 63;
  const int w = tid >> 6;
  const int wm = w >> 2;         // rows wm*32..+31
  const int wn = w & 3;          // cols wn*64..+63
  const int brow = blockIdx.x * 64;

  f4_t acc[2][4];
#pragma unroll
  for (int i = 0; i < 2; ++i)
#pragma unroll
    for (int j = 0; j < 4; ++j) acc[i][j] = (f4_t){0.f, 0.f, 0.f, 0.f};

  for (int kb = 0; kb < KCAT; kb += 64) {
    {
      int r = tid >> 3, c8 = tid & 7;
      int grow = brow + r;
      bf8_t v = {0, 0, 0, 0, 0, 0, 0, 0};
      if (grow < NN) v = *(const bf8_t*)(Zc + (size_t)grow * KCAT + kb + c8 * 8);
      *(bf8_t*)(At + r * 128 + ((c8 * 16) ^ ((r & 7) << 4))) = v;
    }
#pragma unroll
    for (int it = 0; it < 4; ++it) {
      int slot = tid + it * 512;
      int n = slot >> 3, c8 = slot & 7;
      bf8_t v = *(const bf8_t*)(Wc + (size_t)n * KCAT + kb + c8 * 8);
      *(bf8_t*)(Bt + n * 128 + ((c8 * 16) ^ ((n & 7) << 4))) = v;
    }
    __syncthreads();
#pragma unroll
    for (int ks = 0; ks < 2; ++ks) {
      const int kbyte = ks * 64 + (lane >> 4) * 16;
      bf8_t af[2], bfr[4];
#pragma unroll
      for (int mi = 0; mi < 2; ++mi) {
        int m = wm * 32 + mi * 16 + (lane & 15);
        af[mi] = *(const bf8_t*)(At + m * 128 + (kbyte ^ ((m & 7) << 4)));
      }
#pragma unroll
      for (int ni = 0; ni < 4; ++ni) {
        int n = wn * 64 + ni * 16 + (lane & 15);
        bfr[ni] = *(const bf8_t*)(Bt + n * 128 + (kbyte ^ ((n & 7) << 4)));
      }
#pragma unroll
      for (int mi = 0; mi < 2; ++mi)
#pragma unroll
        for (int ni = 0; ni < 4; ++ni)
          acc[mi][ni] = __builtin_amdgcn_mfma_f32_16x16x32_bf16(
              af[mi], bfr[ni], acc[mi][ni], 0, 0, 0);
    }
    __syncthreads();
  }

  const int rq = (lane >> 4) * 4;
  const int cl = lane & 15;
#pragma unroll
  for (int ni = 0; ni < 4; ++ni) {
    int c = wn * 64 + ni * 16 + cl;
    float bv = bias[c];
#pragma unroll
    for (int mi = 0; mi < 2; ++mi) {
#pragma unroll
      for (int j = 0; j < 4; ++j) {
        int row = brow + wm * 32 + mi * 16 + rq + j;
        if (row < NN) {
          size_t o = (size_t)row * HID + c;
          float v = acc[mi][ni][j] + bv;
          if (EPI == 0) C[o] = v;
          else          hb[o] = f2bf(fmaxf(v, 0.f));
        }
      }
    }
  }
}

// ---------------- CSR build ----------------
__global__ __launch_bounds__(256) void hist_k(const int* __restrict__ dst,
                                              const int* __restrict__ et,
                                              int* __restrict__ counts) {
  int e = blockIdx.x * 256 + threadIdx.x;
  if (e < NE) atomicAdd(&counts[dst[e] * NR + et[e]], 1);
}

// merged scan: local scan -> publish sums -> resident-grid spin -> add base.
// 157 blocks (all co-resident), writes offs AND cursor.
__global__ __launch_bounds__(256) void scan_all(
    const int* __restrict__ counts, int* __restrict__ offs,
    int* __restrict__ cursor, int* __restrict__ bsums,
    int* __restrict__ counter) {
  __shared__ int sh[256];
  __shared__ int base_sh;
  const int bid = blockIdx.x;
  const int t = threadIdx.x;
  const int gbase = bid * 1024;
  int v[4], run[4];
  int s = 0;
#pragma unroll
  for (int j = 0; j < 4; ++j) {
    int idx = gbase + t * 4 + j;
    v[j] = (idx < NK) ? counts[idx] : 0;
    s += v[j];
  }
  sh[t] = s;
  __syncthreads();
  for (int off = 1; off < 256; off <<= 1) {
    int x = (t >= off) ? sh[t - off] : 0;
    __syncthreads();
    sh[t] += x;
    __syncthreads();
  }
  {
    int r = sh[t] - s;
#pragma unroll
    for (int j = 0; j < 4; ++j) { run[j] = r; r += v[j]; }
  }
  if (t == 255) {
    bsums[bid] = sh[255];
    __threadfence();
    atomicAdd(counter, 1);
  }
  if (t == 0) {
    while (atomicAdd(counter, 0) < (int)gridDim.x) {}
    __threadfence();
    int b = 0;
    for (int j = 0; j < bid; ++j) b += atomicAdd(&bsums[j], 0);
    base_sh = b;
  }
  __syncthreads();
  const int base = base_sh;
#pragma unroll
  for (int j = 0; j < 4; ++j) {
    int idx = gbase + t * 4 + j;
    if (idx < NK) {
      int val = run[j] + base;
      offs[idx] = val;
      cursor[idx] = val;
    }
  }
  if (bid == 0 && t == 0) offs[NK] = NE;
}

__global__ __launch_bounds__(256) void fill_k(const int* __restrict__ src,
                                              const int* __restrict__ dst,
                                              const int* __restrict__ et,
                                              int* __restrict__ cursor,
                                              unsigned short* __restrict__ ssrc) {
  int e = blockIdx.x * 256 + threadIdx.x;
  if (e < NE) {
    int key = dst[e] * NR + et[e];
    int p = atomicAdd(&cursor[key], 1);
    ssrc[p] = (unsigned short)src[e];
  }
}

extern "C" void kernel_launch(void* const* d_in, const int* in_sizes, int n_in,
                              void* d_out, int out_size, void* d_ws, size_t ws_size,
                              hipStream_t stream) {
  const int*   srcp      = (const int*)d_in[0];
  const int*   dstp      = (const int*)d_in[1];
  const int*   etypep    = (const int*)d_in[2];
  const float* poi_dist  = (const float*)d_in[3];
  const float* time_dist = (const float*)d_in[4];
  const float* road_feat = (const float*)d_in[5];
  const float* poi_w     = (const float*)d_in[6];
  const float* poi_b     = (const float*)d_in[7];
  const float* time_w    = (const float*)d_in[8];
  const float* time_b    = (const float*)d_in[9];
  const float* road_w    = (const float*)d_in[10];
  const float* road_b    = (const float*)d_in[11];
  const float* basis1    = (const float*)d_in[12];
  const float* coef1     = (const float*)d_in[13];
  const float* loop_w1   = (const float*)d_in[14];
  const float* bias1     = (const float*)d_in[15];
  const float* basis2    = (const float*)d_in[16];
  const float* coef2     = (const float*)d_in[17];
  const float* loop_w2   = (const float*)d_in[18];
  const float* bias2     = (const float*)d_in[19];

  float* out = (float*)d_out;

  // ws layout (bytes), total ~109 MB (ws_size ~921 MB):
  //   Wc1  bf16 @ 0           (1,179,648)   [256][2304]
  //   Wc2  bf16 @ 1,179,648   (1,179,648)
  //   TWT  bf16 @ 2,359,296   (737,280)
  //   hbuf bf16 @ 3,096,576   (10,240,000)  feat; then relu(h1)
  //   Zcat bf16 @ 13,336,576  (92,160,000)  [NN][2304]
  //   offs      @ 105,496,576 (640,016)
  //   bsums     @ 106,136,592 (1,024)
  //   ssrc u16  @ 106,137,616 (1,280,000)
  //   cursor    @ 107,417,616 (640,000)
  // aliases: counts+counter -> Zcat region (dead before Zcat's first write)
  char* ws = (char*)d_ws;
  unsigned short* Wc1    = (unsigned short*)(ws);
  unsigned short* Wc2    = (unsigned short*)(ws + 1179648);
  unsigned short* TWT    = (unsigned short*)(ws + 2359296);
  unsigned short* hbuf   = (unsigned short*)(ws + 3096576);
  unsigned short* Zcat   = (unsigned short*)(ws + 13336576);
  int*            offs   = (int*)  (ws + 105496576);
  int*            bsums  = (int*)  (ws + 106136592);
  unsigned short* ssrc   = (unsigned short*)(ws + 106137616);
  int*            cursor = (int*)  (ws + 107417616);
  int*            counts = (int*)Zcat;        // NK ints
  int*            counter = counts + NK;      // 1 int (spin counter)

  dim3 blk(256);

  // ---- CSR build: memset -> hist -> merged scan -> fill (4 launches) ----
  hipMemsetAsync(counts, 0, (NK + 1) * sizeof(int), stream);
  hist_k<<<NE / 256, blk, 0, stream>>>(dstp, etypep, counts);
  scan_all<<<(NK + 1023) / 1024, blk, 0, stream>>>(counts, offs, cursor,
                                                   bsums, counter);
  fill_k<<<NE / 256, blk, 0, stream>>>(srcp, dstp, etypep, cursor, ssrc);

  // ---- weight prep + poi/road projections (one launch) ----
  prep_proj_k<<<1004, blk, 0, stream>>>(loop_w1, loop_w2, time_w,
                                        coef1, basis1, coef2, basis2,
                                        poi_dist, poi_w, poi_b,
                                        road_feat, road_w, road_b,
                                        Wc1, Wc2, TWT, hbuf);

  // ---- time projection (single pass, in-block split-K) ----
  mfma_time2<<<NN / 32, 512, 0, stream>>>(time_dist, TWT, time_b, hbuf);

  // ---- layer 1 ----
  agg_k<<<NN * 64 / 256, blk, 0, stream>>>(offs, ssrc, hbuf, Zcat);
  gemm_cat<1><<<(NN + 63) / 64, 512, 0, stream>>>(Zcat, Wc1, bias1, nullptr, hbuf);

  // ---- layer 2 ----
  agg_k<<<NN * 64 / 256, blk, 0, stream>>>(offs, ssrc, hbuf, Zcat);
  gemm_cat<0><<<(NN + 63) / 64, 512, 0, stream>>>(Zcat, Wc2, bias2, out, nullptr);
}